// Round 1
// baseline (3049.711 us; speedup 1.0000x reference)
//
#include <hip/hip_runtime.h>
#include <math.h>

#define BATCH   4
#define SEQLEN  4096
#define NDIM    256
#define DINNER  512
#define DSTATE  16
#define M_ROWS  (BATCH*SEQLEN)   // 16384

// ---------------------------------------------------------------------------
// K1: x (16384x256) @ x_proj (256x1024) -> silu -> U (cols 0..511), G (512..1023)
// 64x64 tile, 256 threads, 4x4 microtile, fp32.
// ---------------------------------------------------------------------------
__global__ __launch_bounds__(256)
void gemm_k1(const float* __restrict__ X, const float* __restrict__ W,
             float* __restrict__ U, float* __restrict__ G) {
    __shared__ float As[16][68];   // As[k][m], +4 pad
    __shared__ float Bs[16][68];   // Bs[k][n]
    const int tid = threadIdx.x;
    const int tx = tid & 15;       // n quad
    const int ty = tid >> 4;       // m quad
    const int n0 = blockIdx.x * 64;
    const int m0 = blockIdx.y * 64;
    float acc[4][4] = {};
    const int a_k = tid & 15;
    const int a_m = tid >> 4;      // 0..15
    const int b_n = tid & 63;
    const int b_k = tid >> 6;      // 0..3
    for (int k0 = 0; k0 < 256; k0 += 16) {
        #pragma unroll
        for (int i = 0; i < 4; i++)
            As[a_k][a_m + 16*i] = X[(size_t)(m0 + a_m + 16*i)*256 + k0 + a_k];
        #pragma unroll
        for (int i = 0; i < 4; i++)
            Bs[b_k + 4*i][b_n] = W[(size_t)(k0 + b_k + 4*i)*1024 + n0 + b_n];
        __syncthreads();
        #pragma unroll
        for (int k = 0; k < 16; k++) {
            float a[4], b[4];
            #pragma unroll
            for (int i = 0; i < 4; i++) a[i] = As[k][ty*4 + i];
            #pragma unroll
            for (int j = 0; j < 4; j++) b[j] = Bs[k][tx*4 + j];
            #pragma unroll
            for (int i = 0; i < 4; i++)
                #pragma unroll
                for (int j = 0; j < 4; j++)
                    acc[i][j] += a[i] * b[j];
        }
        __syncthreads();
    }
    #pragma unroll
    for (int i = 0; i < 4; i++) {
        const int m = m0 + ty*4 + i;
        #pragma unroll
        for (int j = 0; j < 4; j++) {
            const int n = n0 + tx*4 + j;
            float v = acc[i][j];
            float sv = v / (1.f + expf(-v));   // silu
            if (n < DINNER) U[(size_t)m*DINNER + n] = sv;
            else            G[(size_t)m*DINNER + (n - DINNER)] = sv;
        }
    }
}

// ---------------------------------------------------------------------------
// K2: per-row projections. dt = softplus(u @ dt_proj + bias), Bm = u @ B_proj,
// Cm = u @ C_proj. One thread per row (16384 rows), 48 fp32 accumulators,
// weight reads are thread-uniform -> scalar loads.
// ---------------------------------------------------------------------------
__global__ __launch_bounds__(256)
void proj_kernel(const float* __restrict__ Uv, const float* __restrict__ Wdt,
                 const float* __restrict__ Wb, const float* __restrict__ Wc,
                 const float* __restrict__ bias,
                 float* __restrict__ DT, float* __restrict__ BM,
                 float* __restrict__ CM) {
    const int row = blockIdx.x * 256 + threadIdx.x;
    float accd[16] = {}, accb[16] = {}, accc[16] = {};
    const float4* u4 = (const float4*)(Uv + (size_t)row * DINNER);
    for (int k4 = 0; k4 < DINNER/4; k4++) {
        float4 uv = u4[k4];
        #pragma unroll
        for (int kk = 0; kk < 4; kk++) {
            const float uk = ((const float*)&uv)[kk];
            const int k = k4*4 + kk;
            #pragma unroll
            for (int n = 0; n < 16; n++) {
                accd[n] += uk * Wdt[k*16 + n];
                accb[n] += uk * Wb [k*16 + n];
                accc[n] += uk * Wc [k*16 + n];
            }
        }
    }
    #pragma unroll
    for (int n = 0; n < 16; n++) {
        float dv = accd[n] + bias[n];
        dv = (dv > 20.f) ? dv : log1pf(expf(dv));    // softplus
        DT[(size_t)row*16 + n] = dv;
        BM[(size_t)row*16 + n] = accb[n];
        CM[(size_t)row*16 + n] = accc[n];
    }
}

// ---------------------------------------------------------------------------
// K3: selective scan. One thread per chain (b, d, s): 32768 threads.
// Block = 256 threads = 16 d x 16 s; width-16 shfl reduction over s.
// Fused: y' = (y + u*D) * g  (g = silu(z) precomputed).
// ---------------------------------------------------------------------------
__global__ __launch_bounds__(256)
void scan_kernel(const float* __restrict__ DT, const float* __restrict__ BM,
                 const float* __restrict__ CM, const float* __restrict__ Uv,
                 const float* __restrict__ G, const float* __restrict__ Alog,
                 const float* __restrict__ Dvec, float* __restrict__ Y2) {
    const int tid = threadIdx.x;
    const int s  = tid & 15;
    const int dl = tid >> 4;               // 0..15
    const int blk = blockIdx.x;            // 0..127
    const int b  = blk >> 5;               // 0..3
    const int dg = blk & 31;               // 0..31
    const int d  = dg*16 + dl;             // 0..511
    const float A  = -expf(Alog[(size_t)d*16 + s]);
    const float Dd = Dvec[d];
    float h = 0.f;
    const float* dtp = DT + (size_t)(b*SEQLEN)*16 + s;
    const float* bp  = BM + (size_t)(b*SEQLEN)*16 + s;
    const float* cp  = CM + (size_t)(b*SEQLEN)*16 + s;
    const float* up  = Uv + (size_t)(b*SEQLEN)*DINNER + d;
    const float* gp  = G  + (size_t)(b*SEQLEN)*DINNER + d;
    float*       yp  = Y2 + (size_t)(b*SEQLEN)*DINNER + d;
    for (int l = 0; l < SEQLEN; l++) {
        const float dt = dtp[(size_t)l*16];
        const float Bv = bp [(size_t)l*16];
        const float Cv = cp [(size_t)l*16];
        const float uv = up [(size_t)l*DINNER];
        const float dA = expf(dt * A);
        h = dA*h + (dt*Bv)*uv;
        float p = h * Cv;
        p += __shfl_xor(p, 8, 16);
        p += __shfl_xor(p, 4, 16);
        p += __shfl_xor(p, 2, 16);
        p += __shfl_xor(p, 1, 16);
        if (s == 0) {
            const float g = gp[(size_t)l*DINNER];
            yp[(size_t)l*DINNER] = (p + uv*Dd) * g;
        }
    }
}

// ---------------------------------------------------------------------------
// K4: y' (16384x512) @ out_proj (512x256) -> out. Same tiling as K1.
// ---------------------------------------------------------------------------
__global__ __launch_bounds__(256)
void gemm_k4(const float* __restrict__ Yv, const float* __restrict__ W,
             float* __restrict__ Out) {
    __shared__ float As[16][68];
    __shared__ float Bs[16][68];
    const int tid = threadIdx.x;
    const int tx = tid & 15;
    const int ty = tid >> 4;
    const int n0 = blockIdx.x * 64;   // 0..3 tiles (N=256)
    const int m0 = blockIdx.y * 64;
    float acc[4][4] = {};
    const int a_k = tid & 15;
    const int a_m = tid >> 4;
    const int b_n = tid & 63;
    const int b_k = tid >> 6;
    for (int k0 = 0; k0 < DINNER; k0 += 16) {
        #pragma unroll
        for (int i = 0; i < 4; i++)
            As[a_k][a_m + 16*i] = Yv[(size_t)(m0 + a_m + 16*i)*DINNER + k0 + a_k];
        #pragma unroll
        for (int i = 0; i < 4; i++)
            Bs[b_k + 4*i][b_n] = W[(size_t)(k0 + b_k + 4*i)*NDIM + n0 + b_n];
        __syncthreads();
        #pragma unroll
        for (int k = 0; k < 16; k++) {
            float a[4], b[4];
            #pragma unroll
            for (int i = 0; i < 4; i++) a[i] = As[k][ty*4 + i];
            #pragma unroll
            for (int j = 0; j < 4; j++) b[j] = Bs[k][tx*4 + j];
            #pragma unroll
            for (int i = 0; i < 4; i++)
                #pragma unroll
                for (int j = 0; j < 4; j++)
                    acc[i][j] += a[i] * b[j];
        }
        __syncthreads();
    }
    #pragma unroll
    for (int i = 0; i < 4; i++) {
        const int m = m0 + ty*4 + i;
        #pragma unroll
        for (int j = 0; j < 4; j++) {
            const int n = n0 + tx*4 + j;
            Out[(size_t)m*NDIM + n] = acc[i][j];
        }
    }
}

// ---------------------------------------------------------------------------
extern "C" void kernel_launch(void* const* d_in, const int* in_sizes, int n_in,
                              void* d_out, int out_size, void* d_ws, size_t ws_size,
                              hipStream_t stream) {
    const float* x        = (const float*)d_in[0];  // (4,4096,256)
    const float* x_proj   = (const float*)d_in[1];  // (256,1024)
    const float* dt_proj  = (const float*)d_in[2];  // (512,16)
    const float* A_log    = (const float*)d_in[3];  // (512,16)
    const float* B_proj   = (const float*)d_in[4];  // (512,16)
    const float* C_proj   = (const float*)d_in[5];  // (512,16)
    const float* Dvec     = (const float*)d_in[6];  // (512,)
    const float* out_proj = (const float*)d_in[7];  // (512,256)
    const float* dt_bias  = (const float*)d_in[8];  // (16,)
    float* out = (float*)d_out;

    float* ws = (float*)d_ws;
    float* U  = ws;                                   // 16384*512
    float* G  = U  + (size_t)M_ROWS*DINNER;           // 16384*512
    float* DT = G  + (size_t)M_ROWS*DINNER;           // 16384*16
    float* BM = DT + (size_t)M_ROWS*DSTATE;
    float* CM = BM + (size_t)M_ROWS*DSTATE;
    float* Y2 = CM + (size_t)M_ROWS*DSTATE;           // 16384*512
    // total ~99 MB of ws

    gemm_k1<<<dim3(16, 256), 256, 0, stream>>>(x, x_proj, U, G);
    proj_kernel<<<dim3(M_ROWS/256), 256, 0, stream>>>(U, dt_proj, B_proj, C_proj,
                                                      dt_bias, DT, BM, CM);
    scan_kernel<<<dim3(128), 256, 0, stream>>>(DT, BM, CM, U, G, A_log, Dvec, Y2);
    gemm_k4<<<dim3(4, 256), 256, 0, stream>>>(Y2, out_proj, out);
}

// Round 2
// 745.302 us; speedup vs baseline: 4.0919x; 4.0919x over previous
//
#include <hip/hip_runtime.h>
#include <math.h>

#define BATCH   4
#define SEQLEN  4096
#define NDIM    256
#define DINNER  512
#define DSTATE  16
#define M_ROWS  (BATCH*SEQLEN)   // 16384
#define CHUNK   64
#define NCHUNK  (SEQLEN/CHUNK)   // 64

// ---------------------------------------------------------------------------
// K1: x (16384x256) @ x_proj (256x1024) -> silu -> U (cols 0..511), G (512..1023)
// ---------------------------------------------------------------------------
__global__ __launch_bounds__(256)
void gemm_k1(const float* __restrict__ X, const float* __restrict__ W,
             float* __restrict__ U, float* __restrict__ G) {
    __shared__ float As[16][68];
    __shared__ float Bs[16][68];
    const int tid = threadIdx.x;
    const int tx = tid & 15;
    const int ty = tid >> 4;
    const int n0 = blockIdx.x * 64;
    const int m0 = blockIdx.y * 64;
    float acc[4][4] = {};
    const int a_k = tid & 15;
    const int a_m = tid >> 4;
    const int b_n = tid & 63;
    const int b_k = tid >> 6;
    for (int k0 = 0; k0 < 256; k0 += 16) {
        #pragma unroll
        for (int i = 0; i < 4; i++)
            As[a_k][a_m + 16*i] = X[(size_t)(m0 + a_m + 16*i)*256 + k0 + a_k];
        #pragma unroll
        for (int i = 0; i < 4; i++)
            Bs[b_k + 4*i][b_n] = W[(size_t)(k0 + b_k + 4*i)*1024 + n0 + b_n];
        __syncthreads();
        #pragma unroll
        for (int k = 0; k < 16; k++) {
            float a[4], b[4];
            #pragma unroll
            for (int i = 0; i < 4; i++) a[i] = As[k][ty*4 + i];
            #pragma unroll
            for (int j = 0; j < 4; j++) b[j] = Bs[k][tx*4 + j];
            #pragma unroll
            for (int i = 0; i < 4; i++)
                #pragma unroll
                for (int j = 0; j < 4; j++)
                    acc[i][j] += a[i] * b[j];
        }
        __syncthreads();
    }
    #pragma unroll
    for (int i = 0; i < 4; i++) {
        const int m = m0 + ty*4 + i;
        #pragma unroll
        for (int j = 0; j < 4; j++) {
            const int n = n0 + tx*4 + j;
            float v = acc[i][j];
            float sv = v / (1.f + expf(-v));
            if (n < DINNER) U[(size_t)m*DINNER + n] = sv;
            else            G[(size_t)m*DINNER + (n - DINNER)] = sv;
        }
    }
}

// ---------------------------------------------------------------------------
// K2: dt = softplus(u @ dt_proj + bias), Bm = u @ B_proj, Cm = u @ C_proj.
// ---------------------------------------------------------------------------
__global__ __launch_bounds__(256)
void proj_kernel(const float* __restrict__ Uv, const float* __restrict__ Wdt,
                 const float* __restrict__ Wb, const float* __restrict__ Wc,
                 const float* __restrict__ bias,
                 float* __restrict__ DT, float* __restrict__ BM,
                 float* __restrict__ CM) {
    const int row = blockIdx.x * 256 + threadIdx.x;
    float accd[16] = {}, accb[16] = {}, accc[16] = {};
    const float4* u4 = (const float4*)(Uv + (size_t)row * DINNER);
    for (int k4 = 0; k4 < DINNER/4; k4++) {
        float4 uv = u4[k4];
        #pragma unroll
        for (int kk = 0; kk < 4; kk++) {
            const float uk = ((const float*)&uv)[kk];
            const int k = k4*4 + kk;
            #pragma unroll
            for (int n = 0; n < 16; n++) {
                accd[n] += uk * Wdt[k*16 + n];
                accb[n] += uk * Wb [k*16 + n];
                accc[n] += uk * Wc [k*16 + n];
            }
        }
    }
    #pragma unroll
    for (int n = 0; n < 16; n++) {
        float dv = accd[n] + bias[n];
        dv = (dv > 20.f) ? dv : log1pf(expf(dv));
        DT[(size_t)row*16 + n] = dv;
        BM[(size_t)row*16 + n] = accb[n];
        CM[(size_t)row*16 + n] = accc[n];
    }
}

// ---------------------------------------------------------------------------
// K3a: chunked scan phase A. One block per (b, d-group, chunk); thread=(dl,s).
// Computes local end-state h_end (h_init=0) and decay product P over the chunk.
// Layout of state arrays: [b][d][chunk][s]  (stride 16 for s, contiguous).
// ---------------------------------------------------------------------------
__global__ __launch_bounds__(256)
void scan_phase_a(const float* __restrict__ DT, const float* __restrict__ BM,
                  const float* __restrict__ Uv, const float* __restrict__ Alog,
                  float* __restrict__ HEND, float* __restrict__ PPROD) {
    const int tid = threadIdx.x;
    const int s  = tid & 15;
    const int dl = tid >> 4;
    const int chunk = blockIdx.x;          // 0..63
    const int dg = blockIdx.y;             // 0..31
    const int b  = blockIdx.z;             // 0..3
    const int d  = dg*16 + dl;
    const float A = -expf(Alog[(size_t)d*16 + s]);
    const int l0 = chunk * CHUNK;
    const float* dtp = DT + ((size_t)(b*SEQLEN + l0))*16 + s;
    const float* bp  = BM + ((size_t)(b*SEQLEN + l0))*16 + s;
    const float* up  = Uv + ((size_t)(b*SEQLEN + l0))*DINNER + d;
    float h = 0.f, P = 1.f;
    for (int l = 0; l < CHUNK; l++) {
        const float dt = dtp[(size_t)l*16];
        const float Bv = bp [(size_t)l*16];
        const float uv = up [(size_t)l*DINNER];
        const float dA = expf(dt * A);
        h = dA*h + (dt*Bv)*uv;
        P *= dA;
    }
    const size_t base = ((size_t)(b*DINNER + d)*NCHUNK + chunk)*16 + s;
    HEND [base] = h;
    PPROD[base] = P;
}

// ---------------------------------------------------------------------------
// K3b: sequential pass over chunks. Thread per (b,d,s) = 32768.
// H0[c] = true initial state of chunk c.  h_{c+1} = P[c]*h_c + HEND[c].
// ---------------------------------------------------------------------------
__global__ __launch_bounds__(256)
void scan_phase_b(const float* __restrict__ HEND, const float* __restrict__ PPROD,
                  float* __restrict__ H0) {
    const int tid = threadIdx.x;
    const int s  = tid & 15;
    const int dl = tid >> 4;
    const int blk = blockIdx.x;            // 0..127
    const int b  = blk >> 5;
    const int dg = blk & 31;
    const int d  = dg*16 + dl;
    const size_t base = (size_t)(b*DINNER + d)*NCHUNK*16 + s;
    float h = 0.f;
    for (int c0 = 0; c0 < NCHUNK; c0 += 8) {
        float Pv[8], Hv[8];
        #pragma unroll
        for (int j = 0; j < 8; j++) {
            Pv[j] = PPROD[base + (size_t)(c0+j)*16];
            Hv[j] = HEND [base + (size_t)(c0+j)*16];
        }
        #pragma unroll
        for (int j = 0; j < 8; j++) {
            H0[base + (size_t)(c0+j)*16] = h;
            h = Pv[j]*h + Hv[j];
        }
    }
}

// ---------------------------------------------------------------------------
// K3c: phase C — rerun each chunk from its true initial state, emit output
// fused with skip (u*D) and gate (g).
// ---------------------------------------------------------------------------
__global__ __launch_bounds__(256)
void scan_phase_c(const float* __restrict__ DT, const float* __restrict__ BM,
                  const float* __restrict__ CM, const float* __restrict__ Uv,
                  const float* __restrict__ G, const float* __restrict__ Alog,
                  const float* __restrict__ Dvec, const float* __restrict__ H0,
                  float* __restrict__ Y2) {
    const int tid = threadIdx.x;
    const int s  = tid & 15;
    const int dl = tid >> 4;
    const int chunk = blockIdx.x;
    const int dg = blockIdx.y;
    const int b  = blockIdx.z;
    const int d  = dg*16 + dl;
    const float A  = -expf(Alog[(size_t)d*16 + s]);
    const float Dd = Dvec[d];
    const int l0 = chunk * CHUNK;
    const float* dtp = DT + ((size_t)(b*SEQLEN + l0))*16 + s;
    const float* bp  = BM + ((size_t)(b*SEQLEN + l0))*16 + s;
    const float* cp  = CM + ((size_t)(b*SEQLEN + l0))*16 + s;
    const float* up  = Uv + ((size_t)(b*SEQLEN + l0))*DINNER + d;
    const float* gp  = G  + ((size_t)(b*SEQLEN + l0))*DINNER + d;
    float*       yp  = Y2 + ((size_t)(b*SEQLEN + l0))*DINNER + d;
    float h = H0[((size_t)(b*DINNER + d)*NCHUNK + chunk)*16 + s];
    for (int l = 0; l < CHUNK; l++) {
        const float dt = dtp[(size_t)l*16];
        const float Bv = bp [(size_t)l*16];
        const float Cv = cp [(size_t)l*16];
        const float uv = up [(size_t)l*DINNER];
        const float dA = expf(dt * A);
        h = dA*h + (dt*Bv)*uv;
        float p = h * Cv;
        p += __shfl_xor(p, 8, 16);
        p += __shfl_xor(p, 4, 16);
        p += __shfl_xor(p, 2, 16);
        p += __shfl_xor(p, 1, 16);
        if (s == 0) {
            const float g = gp[(size_t)l*DINNER];
            yp[(size_t)l*DINNER] = (p + uv*Dd) * g;
        }
    }
}

// ---------------------------------------------------------------------------
// K4: y' (16384x512) @ out_proj (512x256) -> out.
// ---------------------------------------------------------------------------
__global__ __launch_bounds__(256)
void gemm_k4(const float* __restrict__ Yv, const float* __restrict__ W,
             float* __restrict__ Out) {
    __shared__ float As[16][68];
    __shared__ float Bs[16][68];
    const int tid = threadIdx.x;
    const int tx = tid & 15;
    const int ty = tid >> 4;
    const int n0 = blockIdx.x * 64;
    const int m0 = blockIdx.y * 64;
    float acc[4][4] = {};
    const int a_k = tid & 15;
    const int a_m = tid >> 4;
    const int b_n = tid & 63;
    const int b_k = tid >> 6;
    for (int k0 = 0; k0 < DINNER; k0 += 16) {
        #pragma unroll
        for (int i = 0; i < 4; i++)
            As[a_k][a_m + 16*i] = Yv[(size_t)(m0 + a_m + 16*i)*DINNER + k0 + a_k];
        #pragma unroll
        for (int i = 0; i < 4; i++)
            Bs[b_k + 4*i][b_n] = W[(size_t)(k0 + b_k + 4*i)*NDIM + n0 + b_n];
        __syncthreads();
        #pragma unroll
        for (int k = 0; k < 16; k++) {
            float a[4], b[4];
            #pragma unroll
            for (int i = 0; i < 4; i++) a[i] = As[k][ty*4 + i];
            #pragma unroll
            for (int j = 0; j < 4; j++) b[j] = Bs[k][tx*4 + j];
            #pragma unroll
            for (int i = 0; i < 4; i++)
                #pragma unroll
                for (int j = 0; j < 4; j++)
                    acc[i][j] += a[i] * b[j];
        }
        __syncthreads();
    }
    #pragma unroll
    for (int i = 0; i < 4; i++) {
        const int m = m0 + ty*4 + i;
        #pragma unroll
        for (int j = 0; j < 4; j++) {
            const int n = n0 + tx*4 + j;
            Out[(size_t)m*NDIM + n] = acc[i][j];
        }
    }
}

// ---------------------------------------------------------------------------
extern "C" void kernel_launch(void* const* d_in, const int* in_sizes, int n_in,
                              void* d_out, int out_size, void* d_ws, size_t ws_size,
                              hipStream_t stream) {
    const float* x        = (const float*)d_in[0];
    const float* x_proj   = (const float*)d_in[1];
    const float* dt_proj  = (const float*)d_in[2];
    const float* A_log    = (const float*)d_in[3];
    const float* B_proj   = (const float*)d_in[4];
    const float* C_proj   = (const float*)d_in[5];
    const float* Dvec     = (const float*)d_in[6];
    const float* out_proj = (const float*)d_in[7];
    const float* dt_bias  = (const float*)d_in[8];
    float* out = (float*)d_out;

    float* ws = (float*)d_ws;
    float* U    = ws;                                    // 16384*512
    float* G    = U    + (size_t)M_ROWS*DINNER;          // 16384*512
    float* DT   = G    + (size_t)M_ROWS*DINNER;          // 16384*16
    float* BM   = DT   + (size_t)M_ROWS*DSTATE;
    float* CM   = BM   + (size_t)M_ROWS*DSTATE;
    float* Y2   = CM   + (size_t)M_ROWS*DSTATE;          // 16384*512
    float* HEND = Y2   + (size_t)M_ROWS*DINNER;          // 4*512*64*16 = 2.1M
    float* PPRO = HEND + (size_t)BATCH*DINNER*NCHUNK*DSTATE;
    float* H0   = PPRO + (size_t)BATCH*DINNER*NCHUNK*DSTATE;
    // total ~129 MB of ws

    gemm_k1<<<dim3(16, 256), 256, 0, stream>>>(x, x_proj, U, G);
    proj_kernel<<<dim3(M_ROWS/256), 256, 0, stream>>>(U, dt_proj, B_proj, C_proj,
                                                      dt_bias, DT, BM, CM);
    scan_phase_a<<<dim3(NCHUNK, 32, BATCH), 256, 0, stream>>>(DT, BM, U, A_log,
                                                              HEND, PPRO);
    scan_phase_b<<<dim3(128), 256, 0, stream>>>(HEND, PPRO, H0);
    scan_phase_c<<<dim3(NCHUNK, 32, BATCH), 256, 0, stream>>>(DT, BM, CM, U, G,
                                                              A_log, Dvec, H0, Y2);
    gemm_k4<<<dim3(4, 256), 256, 0, stream>>>(Y2, out_proj, out);
}

// Round 3
// 580.446 us; speedup vs baseline: 5.2541x; 1.2840x over previous
//
#include <hip/hip_runtime.h>
#include <math.h>

#define BATCH   4
#define SEQLEN  4096
#define NDIM    256
#define DINNER  512
#define DSTATE  16
#define M_ROWS  (BATCH*SEQLEN)   // 16384
#define CHUNK   64
#define NCHUNK  (SEQLEN/CHUNK)   // 64

// ---------------------------------------------------------------------------
// K1: x (16384x256) @ x_proj (256x1024) -> silu -> U (cols 0..511), G (512..1023)
// ---------------------------------------------------------------------------
__global__ __launch_bounds__(256)
void gemm_k1(const float* __restrict__ X, const float* __restrict__ W,
             float* __restrict__ U, float* __restrict__ G) {
    __shared__ float As[16][68];
    __shared__ float Bs[16][68];
    const int tid = threadIdx.x;
    const int tx = tid & 15;
    const int ty = tid >> 4;
    const int n0 = blockIdx.x * 64;
    const int m0 = blockIdx.y * 64;
    float acc[4][4] = {};
    const int a_k = tid & 15;
    const int a_m = tid >> 4;
    const int b_n = tid & 63;
    const int b_k = tid >> 6;
    for (int k0 = 0; k0 < 256; k0 += 16) {
        #pragma unroll
        for (int i = 0; i < 4; i++)
            As[a_k][a_m + 16*i] = X[(size_t)(m0 + a_m + 16*i)*256 + k0 + a_k];
        #pragma unroll
        for (int i = 0; i < 4; i++)
            Bs[b_k + 4*i][b_n] = W[(size_t)(k0 + b_k + 4*i)*1024 + n0 + b_n];
        __syncthreads();
        #pragma unroll
        for (int k = 0; k < 16; k++) {
            float a[4], b[4];
            #pragma unroll
            for (int i = 0; i < 4; i++) a[i] = As[k][ty*4 + i];
            #pragma unroll
            for (int j = 0; j < 4; j++) b[j] = Bs[k][tx*4 + j];
            #pragma unroll
            for (int i = 0; i < 4; i++)
                #pragma unroll
                for (int j = 0; j < 4; j++)
                    acc[i][j] += a[i] * b[j];
        }
        __syncthreads();
    }
    #pragma unroll
    for (int i = 0; i < 4; i++) {
        const int m = m0 + ty*4 + i;
        #pragma unroll
        for (int j = 0; j < 4; j++) {
            const int n = n0 + tx*4 + j;
            float v = acc[i][j];
            float sv = v / (1.f + expf(-v));
            if (n < DINNER) U[(size_t)m*DINNER + n] = sv;
            else            G[(size_t)m*DINNER + (n - DINNER)] = sv;
        }
    }
}

// ---------------------------------------------------------------------------
// K2 (rewritten as tiled GEMM): U (16384x512) @ [Wdt|Wb|Wc] (512x48) ->
// dt = softplus(.+bias) / BM / CM.  64 rows x 48 cols per block, 256 blocks.
// 4x3 microtile per thread.
// ---------------------------------------------------------------------------
__global__ __launch_bounds__(256)
void proj_gemm(const float* __restrict__ Uv, const float* __restrict__ Wdt,
               const float* __restrict__ Wb, const float* __restrict__ Wc,
               const float* __restrict__ bias,
               float* __restrict__ DT, float* __restrict__ BM,
               float* __restrict__ CM) {
    __shared__ float As[16][68];   // [k][m]
    __shared__ float Ws[16][48];   // [k][n] n: 0..15 dt, 16..31 B, 32..47 C
    const int tid = threadIdx.x;
    const int tx = tid & 15;       // n group (3 cols each)
    const int ty = tid >> 4;       // m group (4 rows each)
    const int m0 = blockIdx.x * 64;
    float acc[4][3] = {};
    const int a_k = tid & 15;
    const int a_m = tid >> 4;
    for (int k0 = 0; k0 < DINNER; k0 += 16) {
        #pragma unroll
        for (int i = 0; i < 4; i++)
            As[a_k][a_m + 16*i] = Uv[(size_t)(m0 + a_m + 16*i)*DINNER + k0 + a_k];
        #pragma unroll
        for (int j = 0; j < 3; j++) {
            const int idx = tid + 256*j;          // 0..767
            const int kk = idx / 48;
            const int nn = idx - kk*48;
            float w;
            if      (nn < 16) w = Wdt[(size_t)(k0 + kk)*16 + nn];
            else if (nn < 32) w = Wb [(size_t)(k0 + kk)*16 + (nn - 16)];
            else              w = Wc [(size_t)(k0 + kk)*16 + (nn - 32)];
            Ws[kk][nn] = w;
        }
        __syncthreads();
        #pragma unroll
        for (int k = 0; k < 16; k++) {
            float a[4], w[3];
            #pragma unroll
            for (int i = 0; i < 4; i++) a[i] = As[k][ty*4 + i];
            #pragma unroll
            for (int j = 0; j < 3; j++) w[j] = Ws[k][tx*3 + j];
            #pragma unroll
            for (int i = 0; i < 4; i++)
                #pragma unroll
                for (int j = 0; j < 3; j++)
                    acc[i][j] += a[i] * w[j];
        }
        __syncthreads();
    }
    #pragma unroll
    for (int i = 0; i < 4; i++) {
        const int m = m0 + ty*4 + i;
        #pragma unroll
        for (int j = 0; j < 3; j++) {
            const int n = tx*3 + j;
            float v = acc[i][j];
            if (n < 16) {
                float dv = v + bias[n];
                dv = (dv > 20.f) ? dv : log1pf(expf(dv));
                DT[(size_t)m*16 + n] = dv;
            } else if (n < 32) {
                BM[(size_t)m*16 + (n - 16)] = v;
            } else {
                CM[(size_t)m*16 + (n - 32)] = v;
            }
        }
    }
}

// ---------------------------------------------------------------------------
// K3a: chunked scan phase A. One block per (b, d-group, chunk); thread=(dl,s).
// ---------------------------------------------------------------------------
__global__ __launch_bounds__(256)
void scan_phase_a(const float* __restrict__ DT, const float* __restrict__ BM,
                  const float* __restrict__ Uv, const float* __restrict__ Alog,
                  float* __restrict__ HEND, float* __restrict__ PPROD) {
    const int tid = threadIdx.x;
    const int s  = tid & 15;
    const int dl = tid >> 4;
    const int chunk = blockIdx.x;
    const int dg = blockIdx.y;
    const int b  = blockIdx.z;
    const int d  = dg*16 + dl;
    const float A = -expf(Alog[(size_t)d*16 + s]);
    const int l0 = chunk * CHUNK;
    const float* dtp = DT + ((size_t)(b*SEQLEN + l0))*16 + s;
    const float* bp  = BM + ((size_t)(b*SEQLEN + l0))*16 + s;
    const float* up  = Uv + ((size_t)(b*SEQLEN + l0))*DINNER + d;
    float h = 0.f, P = 1.f;
    for (int l = 0; l < CHUNK; l++) {
        const float dt = dtp[(size_t)l*16];
        const float Bv = bp [(size_t)l*16];
        const float uv = up [(size_t)l*DINNER];
        const float dA = expf(dt * A);
        h = dA*h + (dt*Bv)*uv;
        P *= dA;
    }
    const size_t base = ((size_t)(b*DINNER + d)*NCHUNK + chunk)*16 + s;
    HEND [base] = h;
    PPROD[base] = P;
}

// ---------------------------------------------------------------------------
// K3b: sequential pass over chunks. Thread per (b,d,s) = 32768.
// ---------------------------------------------------------------------------
__global__ __launch_bounds__(256)
void scan_phase_b(const float* __restrict__ HEND, const float* __restrict__ PPROD,
                  float* __restrict__ H0) {
    const int tid = threadIdx.x;
    const int s  = tid & 15;
    const int dl = tid >> 4;
    const int blk = blockIdx.x;
    const int b  = blk >> 5;
    const int dg = blk & 31;
    const int d  = dg*16 + dl;
    const size_t base = (size_t)(b*DINNER + d)*NCHUNK*16 + s;
    float h = 0.f;
    for (int c0 = 0; c0 < NCHUNK; c0 += 8) {
        float Pv[8], Hv[8];
        #pragma unroll
        for (int j = 0; j < 8; j++) {
            Pv[j] = PPROD[base + (size_t)(c0+j)*16];
            Hv[j] = HEND [base + (size_t)(c0+j)*16];
        }
        #pragma unroll
        for (int j = 0; j < 8; j++) {
            H0[base + (size_t)(c0+j)*16] = h;
            h = Pv[j]*h + Hv[j];
        }
    }
}

// ---------------------------------------------------------------------------
// K3c: phase C — rerun each chunk from its true initial state, emit output
// fused with skip (u*D) and gate (g).
// ---------------------------------------------------------------------------
__global__ __launch_bounds__(256)
void scan_phase_c(const float* __restrict__ DT, const float* __restrict__ BM,
                  const float* __restrict__ CM, const float* __restrict__ Uv,
                  const float* __restrict__ G, const float* __restrict__ Alog,
                  const float* __restrict__ Dvec, const float* __restrict__ H0,
                  float* __restrict__ Y2) {
    const int tid = threadIdx.x;
    const int s  = tid & 15;
    const int dl = tid >> 4;
    const int chunk = blockIdx.x;
    const int dg = blockIdx.y;
    const int b  = blockIdx.z;
    const int d  = dg*16 + dl;
    const float A  = -expf(Alog[(size_t)d*16 + s]);
    const float Dd = Dvec[d];
    const int l0 = chunk * CHUNK;
    const float* dtp = DT + ((size_t)(b*SEQLEN + l0))*16 + s;
    const float* bp  = BM + ((size_t)(b*SEQLEN + l0))*16 + s;
    const float* cp  = CM + ((size_t)(b*SEQLEN + l0))*16 + s;
    const float* up  = Uv + ((size_t)(b*SEQLEN + l0))*DINNER + d;
    const float* gp  = G  + ((size_t)(b*SEQLEN + l0))*DINNER + d;
    float*       yp  = Y2 + ((size_t)(b*SEQLEN + l0))*DINNER + d;
    float h = H0[((size_t)(b*DINNER + d)*NCHUNK + chunk)*16 + s];
    for (int l = 0; l < CHUNK; l++) {
        const float dt = dtp[(size_t)l*16];
        const float Bv = bp [(size_t)l*16];
        const float Cv = cp [(size_t)l*16];
        const float uv = up [(size_t)l*DINNER];
        const float dA = expf(dt * A);
        h = dA*h + (dt*Bv)*uv;
        float p = h * Cv;
        p += __shfl_xor(p, 8, 16);
        p += __shfl_xor(p, 4, 16);
        p += __shfl_xor(p, 2, 16);
        p += __shfl_xor(p, 1, 16);
        if (s == 0) {
            const float g = gp[(size_t)l*DINNER];
            yp[(size_t)l*DINNER] = (p + uv*Dd) * g;
        }
    }
}

// ---------------------------------------------------------------------------
// K4: y' (16384x512) @ out_proj (512x256) -> out.
// ---------------------------------------------------------------------------
__global__ __launch_bounds__(256)
void gemm_k4(const float* __restrict__ Yv, const float* __restrict__ W,
             float* __restrict__ Out) {
    __shared__ float As[16][68];
    __shared__ float Bs[16][68];
    const int tid = threadIdx.x;
    const int tx = tid & 15;
    const int ty = tid >> 4;
    const int n0 = blockIdx.x * 64;
    const int m0 = blockIdx.y * 64;
    float acc[4][4] = {};
    const int a_k = tid & 15;
    const int a_m = tid >> 4;
    const int b_n = tid & 63;
    const int b_k = tid >> 6;
    for (int k0 = 0; k0 < DINNER; k0 += 16) {
        #pragma unroll
        for (int i = 0; i < 4; i++)
            As[a_k][a_m + 16*i] = Yv[(size_t)(m0 + a_m + 16*i)*DINNER + k0 + a_k];
        #pragma unroll
        for (int i = 0; i < 4; i++)
            Bs[b_k + 4*i][b_n] = W[(size_t)(k0 + b_k + 4*i)*NDIM + n0 + b_n];
        __syncthreads();
        #pragma unroll
        for (int k = 0; k < 16; k++) {
            float a[4], b[4];
            #pragma unroll
            for (int i = 0; i < 4; i++) a[i] = As[k][ty*4 + i];
            #pragma unroll
            for (int j = 0; j < 4; j++) b[j] = Bs[k][tx*4 + j];
            #pragma unroll
            for (int i = 0; i < 4; i++)
                #pragma unroll
                for (int j = 0; j < 4; j++)
                    acc[i][j] += a[i] * b[j];
        }
        __syncthreads();
    }
    #pragma unroll
    for (int i = 0; i < 4; i++) {
        const int m = m0 + ty*4 + i;
        #pragma unroll
        for (int j = 0; j < 4; j++) {
            const int n = n0 + tx*4 + j;
            Out[(size_t)m*NDIM + n] = acc[i][j];
        }
    }
}

// ---------------------------------------------------------------------------
extern "C" void kernel_launch(void* const* d_in, const int* in_sizes, int n_in,
                              void* d_out, int out_size, void* d_ws, size_t ws_size,
                              hipStream_t stream) {
    const float* x        = (const float*)d_in[0];
    const float* x_proj   = (const float*)d_in[1];
    const float* dt_proj  = (const float*)d_in[2];
    const float* A_log    = (const float*)d_in[3];
    const float* B_proj   = (const float*)d_in[4];
    const float* C_proj   = (const float*)d_in[5];
    const float* Dvec     = (const float*)d_in[6];
    const float* out_proj = (const float*)d_in[7];
    const float* dt_bias  = (const float*)d_in[8];
    float* out = (float*)d_out;

    float* ws = (float*)d_ws;
    float* U    = ws;                                    // 16384*512
    float* G    = U    + (size_t)M_ROWS*DINNER;          // 16384*512
    float* DT   = G    + (size_t)M_ROWS*DINNER;          // 16384*16
    float* BM   = DT   + (size_t)M_ROWS*DSTATE;
    float* CM   = BM   + (size_t)M_ROWS*DSTATE;
    float* Y2   = CM   + (size_t)M_ROWS*DSTATE;          // 16384*512
    float* HEND = Y2   + (size_t)M_ROWS*DINNER;
    float* PPRO = HEND + (size_t)BATCH*DINNER*NCHUNK*DSTATE;
    float* H0   = PPRO + (size_t)BATCH*DINNER*NCHUNK*DSTATE;

    gemm_k1<<<dim3(16, 256), 256, 0, stream>>>(x, x_proj, U, G);
    proj_gemm<<<dim3(M_ROWS/64), 256, 0, stream>>>(U, dt_proj, B_proj, C_proj,
                                                   dt_bias, DT, BM, CM);
    scan_phase_a<<<dim3(NCHUNK, 32, BATCH), 256, 0, stream>>>(DT, BM, U, A_log,
                                                              HEND, PPRO);
    scan_phase_b<<<dim3(128), 256, 0, stream>>>(HEND, PPRO, H0);
    scan_phase_c<<<dim3(NCHUNK, 32, BATCH), 256, 0, stream>>>(DT, BM, CM, U, G,
                                                              A_log, Dvec, H0, Y2);
    gemm_k4<<<dim3(4, 256), 256, 0, stream>>>(Y2, out_proj, out);
}

// Round 4
// 438.439 us; speedup vs baseline: 6.9558x; 1.3239x over previous
//
#include <hip/hip_runtime.h>
#include <math.h>

#define BATCH   4
#define SEQLEN  4096
#define NDIM    256
#define DINNER  512
#define DSTATE  16
#define M_ROWS  (BATCH*SEQLEN)   // 16384
#define CHUNK   64
#define NCHUNK  (SEQLEN/CHUNK)   // 64

// ---------------------------------------------------------------------------
// K1: x (16384x256) @ x_proj (256x1024) -> silu -> U (cols 0..511), G (512..1023)
// ---------------------------------------------------------------------------
__global__ __launch_bounds__(256)
void gemm_k1(const float* __restrict__ X, const float* __restrict__ W,
             float* __restrict__ U, float* __restrict__ G) {
    __shared__ float As[16][68];
    __shared__ float Bs[16][68];
    const int tid = threadIdx.x;
    const int tx = tid & 15;
    const int ty = tid >> 4;
    const int n0 = blockIdx.x * 64;
    const int m0 = blockIdx.y * 64;
    float acc[4][4] = {};
    const int a_k = tid & 15;
    const int a_m = tid >> 4;
    const int b_n = tid & 63;
    const int b_k = tid >> 6;
    for (int k0 = 0; k0 < 256; k0 += 16) {
        #pragma unroll
        for (int i = 0; i < 4; i++)
            As[a_k][a_m + 16*i] = X[(size_t)(m0 + a_m + 16*i)*256 + k0 + a_k];
        #pragma unroll
        for (int i = 0; i < 4; i++)
            Bs[b_k + 4*i][b_n] = W[(size_t)(k0 + b_k + 4*i)*1024 + n0 + b_n];
        __syncthreads();
        #pragma unroll
        for (int k = 0; k < 16; k++) {
            float a[4], b[4];
            #pragma unroll
            for (int i = 0; i < 4; i++) a[i] = As[k][ty*4 + i];
            #pragma unroll
            for (int j = 0; j < 4; j++) b[j] = Bs[k][tx*4 + j];
            #pragma unroll
            for (int i = 0; i < 4; i++)
                #pragma unroll
                for (int j = 0; j < 4; j++)
                    acc[i][j] += a[i] * b[j];
        }
        __syncthreads();
    }
    #pragma unroll
    for (int i = 0; i < 4; i++) {
        const int m = m0 + ty*4 + i;
        #pragma unroll
        for (int j = 0; j < 4; j++) {
            const int n = n0 + tx*4 + j;
            float v = acc[i][j];
            float sv = v / (1.f + expf(-v));
            if (n < DINNER) U[(size_t)m*DINNER + n] = sv;
            else            G[(size_t)m*DINNER + (n - DINNER)] = sv;
        }
    }
}

// ---------------------------------------------------------------------------
// K2: U (16384x512) @ [Wdt|Wb|Wc] (512x48) -> DT/BM/CM with softplus on dt.
// ---------------------------------------------------------------------------
__global__ __launch_bounds__(256)
void proj_gemm(const float* __restrict__ Uv, const float* __restrict__ Wdt,
               const float* __restrict__ Wb, const float* __restrict__ Wc,
               const float* __restrict__ bias,
               float* __restrict__ DT, float* __restrict__ BM,
               float* __restrict__ CM) {
    __shared__ float As[16][68];
    __shared__ float Ws[16][48];
    const int tid = threadIdx.x;
    const int tx = tid & 15;
    const int ty = tid >> 4;
    const int m0 = blockIdx.x * 64;
    float acc[4][3] = {};
    const int a_k = tid & 15;
    const int a_m = tid >> 4;
    for (int k0 = 0; k0 < DINNER; k0 += 16) {
        #pragma unroll
        for (int i = 0; i < 4; i++)
            As[a_k][a_m + 16*i] = Uv[(size_t)(m0 + a_m + 16*i)*DINNER + k0 + a_k];
        #pragma unroll
        for (int j = 0; j < 3; j++) {
            const int idx = tid + 256*j;
            const int kk = idx / 48;
            const int nn = idx - kk*48;
            float w;
            if      (nn < 16) w = Wdt[(size_t)(k0 + kk)*16 + nn];
            else if (nn < 32) w = Wb [(size_t)(k0 + kk)*16 + (nn - 16)];
            else              w = Wc [(size_t)(k0 + kk)*16 + (nn - 32)];
            Ws[kk][nn] = w;
        }
        __syncthreads();
        #pragma unroll
        for (int k = 0; k < 16; k++) {
            float a[4], w[3];
            #pragma unroll
            for (int i = 0; i < 4; i++) a[i] = As[k][ty*4 + i];
            #pragma unroll
            for (int j = 0; j < 3; j++) w[j] = Ws[k][tx*3 + j];
            #pragma unroll
            for (int i = 0; i < 4; i++)
                #pragma unroll
                for (int j = 0; j < 3; j++)
                    acc[i][j] += a[i] * w[j];
        }
        __syncthreads();
    }
    #pragma unroll
    for (int i = 0; i < 4; i++) {
        const int m = m0 + ty*4 + i;
        #pragma unroll
        for (int j = 0; j < 3; j++) {
            const int n = tx*3 + j;
            float v = acc[i][j];
            if (n < 16) {
                float dv = v + bias[n];
                dv = (dv > 20.f) ? dv : log1pf(expf(dv));
                DT[(size_t)m*16 + n] = dv;
            } else if (n < 32) {
                BM[(size_t)m*16 + (n - 16)] = v;
            } else {
                CM[(size_t)m*16 + (n - 32)] = v;
            }
        }
    }
}

// ---------------------------------------------------------------------------
// K3a (relayout): one thread per d; all 16 states in registers.
// Grid (NCHUNK, DINNER/256, BATCH), block 256. dt/dtB staged in LDS.
// State arrays layout: [b][chunk][d][s] (16-contiguous per (d)).
// ---------------------------------------------------------------------------
__global__ __launch_bounds__(256)
void scan_phase_a(const float* __restrict__ DT, const float* __restrict__ BM,
                  const float* __restrict__ Uv, const float* __restrict__ Alog,
                  float* __restrict__ HEND, float* __restrict__ PPROD) {
    __shared__ float s_dt[CHUNK][DSTATE];   // 4 KB
    __shared__ float s_db[CHUNK][DSTATE];   // dt*B, 4 KB
    const int tid = threadIdx.x;
    const int chunk = blockIdx.x;
    const int dg = blockIdx.y;
    const int b  = blockIdx.z;
    const int d  = dg*256 + tid;
    const int l0 = chunk * CHUNK;
    {   // stage dt and dt*B: 1024 floats each, 256 threads -> 1 float4 each
        const float4 dtv = ((const float4*)(DT + (size_t)(b*SEQLEN + l0)*16))[tid];
        const float4 bmv = ((const float4*)(BM + (size_t)(b*SEQLEN + l0)*16))[tid];
        ((float4*)&s_dt[0][0])[tid] = dtv;
        float4 dbv;
        dbv.x = dtv.x*bmv.x; dbv.y = dtv.y*bmv.y;
        dbv.z = dtv.z*bmv.z; dbv.w = dtv.w*bmv.w;
        ((float4*)&s_db[0][0])[tid] = dbv;
    }
    __syncthreads();
    float A[DSTATE];
    #pragma unroll
    for (int q = 0; q < 4; q++) {
        const float4 av = ((const float4*)(Alog + (size_t)d*16))[q];
        A[4*q+0] = -__expf(av.x); A[4*q+1] = -__expf(av.y);
        A[4*q+2] = -__expf(av.z); A[4*q+3] = -__expf(av.w);
    }
    float h[DSTATE] = {};
    float P[DSTATE];
    #pragma unroll
    for (int s = 0; s < DSTATE; s++) P[s] = 1.f;
    const float* up = Uv + ((size_t)(b*SEQLEN + l0))*DINNER + d;
    for (int l = 0; l < CHUNK; l++) {
        const float u = up[(size_t)l*DINNER];
        #pragma unroll
        for (int s = 0; s < DSTATE; s++) {
            const float dA = __expf(s_dt[l][s] * A[s]);
            h[s] = dA*h[s] + s_db[l][s]*u;
            P[s] *= dA;
        }
    }
    float* he = HEND  + ((size_t)(b*NCHUNK + chunk)*DINNER + d)*16;
    float* pp = PPROD + ((size_t)(b*NCHUNK + chunk)*DINNER + d)*16;
    #pragma unroll
    for (int q = 0; q < 4; q++) {
        float4 hv, pv;
        hv.x = h[4*q+0]; hv.y = h[4*q+1]; hv.z = h[4*q+2]; hv.w = h[4*q+3];
        pv.x = P[4*q+0]; pv.y = P[4*q+1]; pv.z = P[4*q+2]; pv.w = P[4*q+3];
        ((float4*)he)[q] = hv;
        ((float4*)pp)[q] = pv;
    }
}

// ---------------------------------------------------------------------------
// K3b: sequential chain over chunks. Thread per (b,d,s) = 32768.
// h_{c+1} = P[c]*h_c + HEND[c];  H0[c] = state entering chunk c.
// ---------------------------------------------------------------------------
__global__ __launch_bounds__(256)
void scan_phase_b(const float* __restrict__ HEND, const float* __restrict__ PPROD,
                  float* __restrict__ H0) {
    const int tid = threadIdx.x;
    const int s  = tid & 15;
    const int dl = tid >> 4;
    const int blk = blockIdx.x;
    const int b  = blk >> 5;
    const int dg = blk & 31;
    const int d  = dg*16 + dl;
    float h = 0.f;
    for (int c0 = 0; c0 < NCHUNK; c0 += 8) {
        float Pv[8], Hv[8];
        #pragma unroll
        for (int j = 0; j < 8; j++) {
            const size_t idx = ((size_t)(b*NCHUNK + c0 + j)*DINNER + d)*16 + s;
            Pv[j] = PPROD[idx];
            Hv[j] = HEND [idx];
        }
        #pragma unroll
        for (int j = 0; j < 8; j++) {
            H0[((size_t)(b*NCHUNK + c0 + j)*DINNER + d)*16 + s] = h;
            h = Pv[j]*h + Hv[j];
        }
    }
}

// ---------------------------------------------------------------------------
// K3c (relayout): one thread per d; 16 states in registers; y-reduction is a
// serial accumulator. Fused skip (u*D) and gate (g). dt/dtB/C staged in LDS.
// ---------------------------------------------------------------------------
__global__ __launch_bounds__(256)
void scan_phase_c(const float* __restrict__ DT, const float* __restrict__ BM,
                  const float* __restrict__ CM, const float* __restrict__ Uv,
                  const float* __restrict__ G, const float* __restrict__ Alog,
                  const float* __restrict__ Dvec, const float* __restrict__ H0,
                  float* __restrict__ Y2) {
    __shared__ float s_dt[CHUNK][DSTATE];
    __shared__ float s_db[CHUNK][DSTATE];
    __shared__ float s_c [CHUNK][DSTATE];
    const int tid = threadIdx.x;
    const int chunk = blockIdx.x;
    const int dg = blockIdx.y;
    const int b  = blockIdx.z;
    const int d  = dg*256 + tid;
    const int l0 = chunk * CHUNK;
    {
        const float4 dtv = ((const float4*)(DT + (size_t)(b*SEQLEN + l0)*16))[tid];
        const float4 bmv = ((const float4*)(BM + (size_t)(b*SEQLEN + l0)*16))[tid];
        const float4 cmv = ((const float4*)(CM + (size_t)(b*SEQLEN + l0)*16))[tid];
        ((float4*)&s_dt[0][0])[tid] = dtv;
        float4 dbv;
        dbv.x = dtv.x*bmv.x; dbv.y = dtv.y*bmv.y;
        dbv.z = dtv.z*bmv.z; dbv.w = dtv.w*bmv.w;
        ((float4*)&s_db[0][0])[tid] = dbv;
        ((float4*)&s_c [0][0])[tid] = cmv;
    }
    __syncthreads();
    float A[DSTATE];
    #pragma unroll
    for (int q = 0; q < 4; q++) {
        const float4 av = ((const float4*)(Alog + (size_t)d*16))[q];
        A[4*q+0] = -__expf(av.x); A[4*q+1] = -__expf(av.y);
        A[4*q+2] = -__expf(av.z); A[4*q+3] = -__expf(av.w);
    }
    float h[DSTATE];
    {
        const float* h0 = H0 + ((size_t)(b*NCHUNK + chunk)*DINNER + d)*16;
        #pragma unroll
        for (int q = 0; q < 4; q++) {
            const float4 hv = ((const float4*)h0)[q];
            h[4*q+0] = hv.x; h[4*q+1] = hv.y; h[4*q+2] = hv.z; h[4*q+3] = hv.w;
        }
    }
    const float Dd = Dvec[d];
    const float* up = Uv + ((size_t)(b*SEQLEN + l0))*DINNER + d;
    const float* gp = G  + ((size_t)(b*SEQLEN + l0))*DINNER + d;
    float*       yp = Y2 + ((size_t)(b*SEQLEN + l0))*DINNER + d;
    for (int l = 0; l < CHUNK; l++) {
        const float u = up[(size_t)l*DINNER];
        const float g = gp[(size_t)l*DINNER];
        float y = 0.f;
        #pragma unroll
        for (int s = 0; s < DSTATE; s++) {
            const float dA = __expf(s_dt[l][s] * A[s]);
            h[s] = dA*h[s] + s_db[l][s]*u;
            y += h[s]*s_c[l][s];
        }
        yp[(size_t)l*DINNER] = (y + u*Dd) * g;
    }
}

// ---------------------------------------------------------------------------
// K4: y' (16384x512) @ out_proj (512x256) -> out.
// ---------------------------------------------------------------------------
__global__ __launch_bounds__(256)
void gemm_k4(const float* __restrict__ Yv, const float* __restrict__ W,
             float* __restrict__ Out) {
    __shared__ float As[16][68];
    __shared__ float Bs[16][68];
    const int tid = threadIdx.x;
    const int tx = tid & 15;
    const int ty = tid >> 4;
    const int n0 = blockIdx.x * 64;
    const int m0 = blockIdx.y * 64;
    float acc[4][4] = {};
    const int a_k = tid & 15;
    const int a_m = tid >> 4;
    const int b_n = tid & 63;
    const int b_k = tid >> 6;
    for (int k0 = 0; k0 < DINNER; k0 += 16) {
        #pragma unroll
        for (int i = 0; i < 4; i++)
            As[a_k][a_m + 16*i] = Yv[(size_t)(m0 + a_m + 16*i)*DINNER + k0 + a_k];
        #pragma unroll
        for (int i = 0; i < 4; i++)
            Bs[b_k + 4*i][b_n] = W[(size_t)(k0 + b_k + 4*i)*NDIM + n0 + b_n];
        __syncthreads();
        #pragma unroll
        for (int k = 0; k < 16; k++) {
            float a[4], b[4];
            #pragma unroll
            for (int i = 0; i < 4; i++) a[i] = As[k][ty*4 + i];
            #pragma unroll
            for (int j = 0; j < 4; j++) b[j] = Bs[k][tx*4 + j];
            #pragma unroll
            for (int i = 0; i < 4; i++)
                #pragma unroll
                for (int j = 0; j < 4; j++)
                    acc[i][j] += a[i] * b[j];
        }
        __syncthreads();
    }
    #pragma unroll
    for (int i = 0; i < 4; i++) {
        const int m = m0 + ty*4 + i;
        #pragma unroll
        for (int j = 0; j < 4; j++) {
            const int n = n0 + tx*4 + j;
            Out[(size_t)m*NDIM + n] = acc[i][j];
        }
    }
}

// ---------------------------------------------------------------------------
extern "C" void kernel_launch(void* const* d_in, const int* in_sizes, int n_in,
                              void* d_out, int out_size, void* d_ws, size_t ws_size,
                              hipStream_t stream) {
    const float* x        = (const float*)d_in[0];
    const float* x_proj   = (const float*)d_in[1];
    const float* dt_proj  = (const float*)d_in[2];
    const float* A_log    = (const float*)d_in[3];
    const float* B_proj   = (const float*)d_in[4];
    const float* C_proj   = (const float*)d_in[5];
    const float* Dvec     = (const float*)d_in[6];
    const float* out_proj = (const float*)d_in[7];
    const float* dt_bias  = (const float*)d_in[8];
    float* out = (float*)d_out;

    float* ws = (float*)d_ws;
    float* U    = ws;                                    // 16384*512
    float* G    = U    + (size_t)M_ROWS*DINNER;          // 16384*512
    float* DT   = G    + (size_t)M_ROWS*DINNER;          // 16384*16
    float* BM   = DT   + (size_t)M_ROWS*DSTATE;
    float* CM   = BM   + (size_t)M_ROWS*DSTATE;
    float* Y2   = CM   + (size_t)M_ROWS*DSTATE;          // 16384*512
    float* HEND = Y2   + (size_t)M_ROWS*DINNER;          // [b][chunk][d][s]
    float* PPRO = HEND + (size_t)BATCH*NCHUNK*DINNER*DSTATE;
    float* H0   = PPRO + (size_t)BATCH*NCHUNK*DINNER*DSTATE;

    gemm_k1<<<dim3(16, 256), 256, 0, stream>>>(x, x_proj, U, G);
    proj_gemm<<<dim3(M_ROWS/64), 256, 0, stream>>>(U, dt_proj, B_proj, C_proj,
                                                   dt_bias, DT, BM, CM);
    scan_phase_a<<<dim3(NCHUNK, DINNER/256, BATCH), 256, 0, stream>>>(
        DT, BM, U, A_log, HEND, PPRO);
    scan_phase_b<<<dim3(128), 256, 0, stream>>>(HEND, PPRO, H0);
    scan_phase_c<<<dim3(NCHUNK, DINNER/256, BATCH), 256, 0, stream>>>(
        DT, BM, CM, U, G, A_log, Dvec, H0, Y2);
    gemm_k4<<<dim3(4, 256), 256, 0, stream>>>(Y2, out_proj, out);
}

// Round 5
// 323.123 us; speedup vs baseline: 9.4382x; 1.3569x over previous
//
#include <hip/hip_runtime.h>
#include <math.h>

#define BATCH   4
#define SEQLEN  4096
#define NDIM    256
#define DINNER  512
#define DSTATE  16
#define M_ROWS  (BATCH*SEQLEN)   // 16384
#define CHUNK   64
#define NCHUNK  (SEQLEN/CHUNK)   // 64

typedef unsigned short u16;
typedef short short8 __attribute__((ext_vector_type(8)));
typedef float floatx4 __attribute__((ext_vector_type(4)));

__device__ __forceinline__ u16 f32_to_bf16(float f) {
    union { float f; unsigned u; } v; v.f = f;
    unsigned u = v.u;
    unsigned r = (u + 0x7FFFu + ((u >> 16) & 1u)) >> 16;
    return (u16)r;
}
__device__ __forceinline__ float bf16_to_f32(u16 h) {
    union { unsigned u; float f; } v; v.u = ((unsigned)h) << 16;
    return v.f;
}

// ---------------------------------------------------------------------------
// prep_x: x (M_ROWS x 256 fp32, row-major) -> Xhi/Xlo bf16 row-major.
// 1 float4 per thread.
// ---------------------------------------------------------------------------
__global__ __launch_bounds__(256)
void prep_x(const float* __restrict__ X, u16* __restrict__ Xhi,
            u16* __restrict__ Xlo) {
    const size_t t = (size_t)blockIdx.x * 256 + threadIdx.x;
    const float4 v = ((const float4*)X)[t];
    u16 h[4], l[4];
    const float* vf = (const float*)&v;
    #pragma unroll
    for (int i = 0; i < 4; i++) {
        h[i] = f32_to_bf16(vf[i]);
        l[i] = f32_to_bf16(vf[i] - bf16_to_f32(h[i]));
    }
    uint2 hp, lp;
    hp.x = (unsigned)h[0] | ((unsigned)h[1] << 16);
    hp.y = (unsigned)h[2] | ((unsigned)h[3] << 16);
    lp.x = (unsigned)l[0] | ((unsigned)l[1] << 16);
    lp.y = (unsigned)l[2] | ((unsigned)l[3] << 16);
    ((uint2*)Xhi)[t] = hp;
    ((uint2*)Xlo)[t] = lp;
}

// ---------------------------------------------------------------------------
// prep_w: W (K x N fp32 row-major) -> packed hi/lo bf16 in B-fragment order:
// out[((kb*4+q)*N + n)*8 + j] = W[(kb*32+q*8+j)*N + n].
// One element per thread; writes coalesced.
// ---------------------------------------------------------------------------
template<int N, int LOGN>
__global__ __launch_bounds__(256)
void prep_w(const float* __restrict__ W, u16* __restrict__ Whi,
            u16* __restrict__ Wlo) {
    const int t = blockIdx.x * 256 + threadIdx.x;
    const int j  = t & 7;
    const int n  = (t >> 3) & (N - 1);
    const int q  = (t >> (3 + LOGN)) & 3;
    const int kb = t >> (5 + LOGN);
    const int k  = kb * 32 + q * 8 + j;
    const float v = W[(size_t)k * N + n];
    const u16 hi = f32_to_bf16(v);
    Whi[t] = hi;
    Wlo[t] = f32_to_bf16(v - bf16_to_f32(hi));
}

// ---------------------------------------------------------------------------
// Split-bf16 MFMA GEMM: A (M x KT, hi/lo bf16 row-major) @ W (KT x NT, packed)
// Block tile 128x128, 4 waves (2x2), each wave 64x64 = 4x4 mfma tiles.
// acc = ah*bh + ah*bl + al*bh  (fp32-grade accuracy).
// SILU=true: silu epilogue, split cols into O1 (n<512) / O2 (n>=512).
// ---------------------------------------------------------------------------
template<int NT, int KT, bool SILU>
__global__ __launch_bounds__(256)
void mfma_gemm(const u16* __restrict__ Ahi, const u16* __restrict__ Alo,
               const u16* __restrict__ Whi, const u16* __restrict__ Wlo,
               float* __restrict__ O1, float* __restrict__ O2) {
    __shared__ __attribute__((aligned(16))) u16 sAhi[128 * 40]; // row stride 40
    __shared__ __attribute__((aligned(16))) u16 sAlo[128 * 40];
    const int tid = threadIdx.x;
    const int lane = tid & 63;
    const int w  = tid >> 6;
    const int wm = w >> 1, wn = w & 1;
    const int n0 = blockIdx.x * 128;
    const int m0 = blockIdx.y * 128;
    const int l15 = lane & 15, q = lane >> 4;

    floatx4 acc[4][4];
    const floatx4 zero = {0.f, 0.f, 0.f, 0.f};
    #pragma unroll
    for (int i = 0; i < 4; i++)
        #pragma unroll
        for (int j = 0; j < 4; j++) acc[i][j] = zero;

    for (int kb = 0; kb < KT / 32; kb++) {
        // stage A tile (128 rows x 32 k) hi+lo: 512 16B-chunks each, 2/thread
        #pragma unroll
        for (int i = 0; i < 2; i++) {
            const int idx = tid + 256 * i;
            const int row = idx >> 2, c = idx & 3;
            const size_t off = (size_t)(m0 + row) * KT + kb * 32 + c * 8;
            *(float4*)(sAhi + row * 40 + c * 8) = *(const float4*)(Ahi + off);
            *(float4*)(sAlo + row * 40 + c * 8) = *(const float4*)(Alo + off);
        }
        __syncthreads();

        short8 bh[4], bl[4], ah[4], al[4];
        #pragma unroll
        for (int nt = 0; nt < 4; nt++) {
            const size_t off =
                ((size_t)((kb * 4 + q) * NT) + n0 + wn * 64 + nt * 16 + l15) * 8;
            bh[nt] = *(const short8*)(Whi + off);
            bl[nt] = *(const short8*)(Wlo + off);
        }
        #pragma unroll
        for (int mt = 0; mt < 4; mt++) {
            const int m = wm * 64 + mt * 16 + l15;
            ah[mt] = *(const short8*)(sAhi + m * 40 + q * 8);
            al[mt] = *(const short8*)(sAlo + m * 40 + q * 8);
        }
        #pragma unroll
        for (int mt = 0; mt < 4; mt++)
            #pragma unroll
            for (int nt = 0; nt < 4; nt++) {
                acc[mt][nt] = __builtin_amdgcn_mfma_f32_16x16x32_bf16(
                    ah[mt], bh[nt], acc[mt][nt], 0, 0, 0);
                acc[mt][nt] = __builtin_amdgcn_mfma_f32_16x16x32_bf16(
                    ah[mt], bl[nt], acc[mt][nt], 0, 0, 0);
                acc[mt][nt] = __builtin_amdgcn_mfma_f32_16x16x32_bf16(
                    al[mt], bh[nt], acc[mt][nt], 0, 0, 0);
            }
        __syncthreads();
    }
    // epilogue: D col=lane&15, row=quad*4+reg  [verified m89/m91]
    #pragma unroll
    for (int mt = 0; mt < 4; mt++) {
        #pragma unroll
        for (int nt = 0; nt < 4; nt++) {
            const int col = n0 + wn * 64 + nt * 16 + l15;
            #pragma unroll
            for (int r = 0; r < 4; r++) {
                const int row = m0 + wm * 64 + mt * 16 + q * 4 + r;
                float v = acc[mt][nt][r];
                if (SILU) {
                    v = v / (1.f + expf(-v));
                    if (col < DINNER) O1[(size_t)row * DINNER + col] = v;
                    else              O2[(size_t)row * DINNER + col - DINNER] = v;
                } else {
                    O1[(size_t)row * NT + col] = v;
                }
            }
        }
    }
}

// ---------------------------------------------------------------------------
// K2: U (16384x512) @ [Wdt|Wb|Wc] (512x48) -> DT/BM/CM with softplus on dt.
// ---------------------------------------------------------------------------
__global__ __launch_bounds__(256)
void proj_gemm(const float* __restrict__ Uv, const float* __restrict__ Wdt,
               const float* __restrict__ Wb, const float* __restrict__ Wc,
               const float* __restrict__ bias,
               float* __restrict__ DT, float* __restrict__ BM,
               float* __restrict__ CM) {
    __shared__ float As[16][68];
    __shared__ float Ws[16][48];
    const int tid = threadIdx.x;
    const int tx = tid & 15;
    const int ty = tid >> 4;
    const int m0 = blockIdx.x * 64;
    float acc[4][3] = {};
    const int a_k = tid & 15;
    const int a_m = tid >> 4;
    for (int k0 = 0; k0 < DINNER; k0 += 16) {
        #pragma unroll
        for (int i = 0; i < 4; i++)
            As[a_k][a_m + 16*i] = Uv[(size_t)(m0 + a_m + 16*i)*DINNER + k0 + a_k];
        #pragma unroll
        for (int j = 0; j < 3; j++) {
            const int idx = tid + 256*j;
            const int kk = idx / 48;
            const int nn = idx - kk*48;
            float w;
            if      (nn < 16) w = Wdt[(size_t)(k0 + kk)*16 + nn];
            else if (nn < 32) w = Wb [(size_t)(k0 + kk)*16 + (nn - 16)];
            else              w = Wc [(size_t)(k0 + kk)*16 + (nn - 32)];
            Ws[kk][nn] = w;
        }
        __syncthreads();
        #pragma unroll
        for (int k = 0; k < 16; k++) {
            float a[4], wv[3];
            #pragma unroll
            for (int i = 0; i < 4; i++) a[i] = As[k][ty*4 + i];
            #pragma unroll
            for (int j = 0; j < 3; j++) wv[j] = Ws[k][tx*3 + j];
            #pragma unroll
            for (int i = 0; i < 4; i++)
                #pragma unroll
                for (int j = 0; j < 3; j++)
                    acc[i][j] += a[i] * wv[j];
        }
        __syncthreads();
    }
    #pragma unroll
    for (int i = 0; i < 4; i++) {
        const int m = m0 + ty*4 + i;
        #pragma unroll
        for (int j = 0; j < 3; j++) {
            const int n = tx*3 + j;
            float v = acc[i][j];
            if (n < 16) {
                float dv = v + bias[n];
                dv = (dv > 20.f) ? dv : log1pf(expf(dv));
                DT[(size_t)m*16 + n] = dv;
            } else if (n < 32) {
                BM[(size_t)m*16 + (n - 16)] = v;
            } else {
                CM[(size_t)m*16 + (n - 32)] = v;
            }
        }
    }
}

// ---------------------------------------------------------------------------
// K3a: chunked scan phase A. One thread per d; 16 states in registers.
// ---------------------------------------------------------------------------
__global__ __launch_bounds__(256)
void scan_phase_a(const float* __restrict__ DT, const float* __restrict__ BM,
                  const float* __restrict__ Uv, const float* __restrict__ Alog,
                  float* __restrict__ HEND, float* __restrict__ PPROD) {
    __shared__ float s_dt[CHUNK][DSTATE];
    __shared__ float s_db[CHUNK][DSTATE];
    const int tid = threadIdx.x;
    const int chunk = blockIdx.x;
    const int dg = blockIdx.y;
    const int b  = blockIdx.z;
    const int d  = dg*256 + tid;
    const int l0 = chunk * CHUNK;
    {
        const float4 dtv = ((const float4*)(DT + (size_t)(b*SEQLEN + l0)*16))[tid];
        const float4 bmv = ((const float4*)(BM + (size_t)(b*SEQLEN + l0)*16))[tid];
        ((float4*)&s_dt[0][0])[tid] = dtv;
        float4 dbv;
        dbv.x = dtv.x*bmv.x; dbv.y = dtv.y*bmv.y;
        dbv.z = dtv.z*bmv.z; dbv.w = dtv.w*bmv.w;
        ((float4*)&s_db[0][0])[tid] = dbv;
    }
    __syncthreads();
    float A[DSTATE];
    #pragma unroll
    for (int qq = 0; qq < 4; qq++) {
        const float4 av = ((const float4*)(Alog + (size_t)d*16))[qq];
        A[4*qq+0] = -__expf(av.x); A[4*qq+1] = -__expf(av.y);
        A[4*qq+2] = -__expf(av.z); A[4*qq+3] = -__expf(av.w);
    }
    float h[DSTATE] = {};
    float P[DSTATE];
    #pragma unroll
    for (int s = 0; s < DSTATE; s++) P[s] = 1.f;
    const float* up = Uv + ((size_t)(b*SEQLEN + l0))*DINNER + d;
    for (int l = 0; l < CHUNK; l++) {
        const float u = up[(size_t)l*DINNER];
        #pragma unroll
        for (int s = 0; s < DSTATE; s++) {
            const float dA = __expf(s_dt[l][s] * A[s]);
            h[s] = dA*h[s] + s_db[l][s]*u;
            P[s] *= dA;
        }
    }
    float* he = HEND  + ((size_t)(b*NCHUNK + chunk)*DINNER + d)*16;
    float* pp = PPROD + ((size_t)(b*NCHUNK + chunk)*DINNER + d)*16;
    #pragma unroll
    for (int qq = 0; qq < 4; qq++) {
        float4 hv, pv;
        hv.x = h[4*qq+0]; hv.y = h[4*qq+1]; hv.z = h[4*qq+2]; hv.w = h[4*qq+3];
        pv.x = P[4*qq+0]; pv.y = P[4*qq+1]; pv.z = P[4*qq+2]; pv.w = P[4*qq+3];
        ((float4*)he)[qq] = hv;
        ((float4*)pp)[qq] = pv;
    }
}

// ---------------------------------------------------------------------------
// K3b: sequential chain over chunks. Thread per (b,d,s) = 32768.
// ---------------------------------------------------------------------------
__global__ __launch_bounds__(256)
void scan_phase_b(const float* __restrict__ HEND, const float* __restrict__ PPROD,
                  float* __restrict__ H0) {
    const int tid = threadIdx.x;
    const int s  = tid & 15;
    const int dl = tid >> 4;
    const int blk = blockIdx.x;
    const int b  = blk >> 5;
    const int dg = blk & 31;
    const int d  = dg*16 + dl;
    float h = 0.f;
    for (int c0 = 0; c0 < NCHUNK; c0 += 8) {
        float Pv[8], Hv[8];
        #pragma unroll
        for (int j = 0; j < 8; j++) {
            const size_t idx = ((size_t)(b*NCHUNK + c0 + j)*DINNER + d)*16 + s;
            Pv[j] = PPROD[idx];
            Hv[j] = HEND [idx];
        }
        #pragma unroll
        for (int j = 0; j < 8; j++) {
            H0[((size_t)(b*NCHUNK + c0 + j)*DINNER + d)*16 + s] = h;
            h = Pv[j]*h + Hv[j];
        }
    }
}

// ---------------------------------------------------------------------------
// K3c: rerun chunks from true initial state; emit Y2 as split bf16 hi/lo
// (feeds the MFMA K4). Fused skip (u*D) and gate (g).
// ---------------------------------------------------------------------------
__global__ __launch_bounds__(256)
void scan_phase_c(const float* __restrict__ DT, const float* __restrict__ BM,
                  const float* __restrict__ CM, const float* __restrict__ Uv,
                  const float* __restrict__ G, const float* __restrict__ Alog,
                  const float* __restrict__ Dvec, const float* __restrict__ H0,
                  u16* __restrict__ Y2hi, u16* __restrict__ Y2lo) {
    __shared__ float s_dt[CHUNK][DSTATE];
    __shared__ float s_db[CHUNK][DSTATE];
    __shared__ float s_c [CHUNK][DSTATE];
    const int tid = threadIdx.x;
    const int chunk = blockIdx.x;
    const int dg = blockIdx.y;
    const int b  = blockIdx.z;
    const int d  = dg*256 + tid;
    const int l0 = chunk * CHUNK;
    {
        const float4 dtv = ((const float4*)(DT + (size_t)(b*SEQLEN + l0)*16))[tid];
        const float4 bmv = ((const float4*)(BM + (size_t)(b*SEQLEN + l0)*16))[tid];
        const float4 cmv = ((const float4*)(CM + (size_t)(b*SEQLEN + l0)*16))[tid];
        ((float4*)&s_dt[0][0])[tid] = dtv;
        float4 dbv;
        dbv.x = dtv.x*bmv.x; dbv.y = dtv.y*bmv.y;
        dbv.z = dtv.z*bmv.z; dbv.w = dtv.w*bmv.w;
        ((float4*)&s_db[0][0])[tid] = dbv;
        ((float4*)&s_c [0][0])[tid] = cmv;
    }
    __syncthreads();
    float A[DSTATE];
    #pragma unroll
    for (int qq = 0; qq < 4; qq++) {
        const float4 av = ((const float4*)(Alog + (size_t)d*16))[qq];
        A[4*qq+0] = -__expf(av.x); A[4*qq+1] = -__expf(av.y);
        A[4*qq+2] = -__expf(av.z); A[4*qq+3] = -__expf(av.w);
    }
    float h[DSTATE];
    {
        const float* h0 = H0 + ((size_t)(b*NCHUNK + chunk)*DINNER + d)*16;
        #pragma unroll
        for (int qq = 0; qq < 4; qq++) {
            const float4 hv = ((const float4*)h0)[qq];
            h[4*qq+0] = hv.x; h[4*qq+1] = hv.y; h[4*qq+2] = hv.z; h[4*qq+3] = hv.w;
        }
    }
    const float Dd = Dvec[d];
    const float* up = Uv + ((size_t)(b*SEQLEN + l0))*DINNER + d;
    const float* gp = G  + ((size_t)(b*SEQLEN + l0))*DINNER + d;
    u16* yhp = Y2hi + ((size_t)(b*SEQLEN + l0))*DINNER + d;
    u16* ylp = Y2lo + ((size_t)(b*SEQLEN + l0))*DINNER + d;
    for (int l = 0; l < CHUNK; l++) {
        const float u = up[(size_t)l*DINNER];
        const float g = gp[(size_t)l*DINNER];
        float y = 0.f;
        #pragma unroll
        for (int s = 0; s < DSTATE; s++) {
            const float dA = __expf(s_dt[l][s] * A[s]);
            h[s] = dA*h[s] + s_db[l][s]*u;
            y += h[s]*s_c[l][s];
        }
        const float yv = (y + u*Dd) * g;
        const u16 hi = f32_to_bf16(yv);
        yhp[(size_t)l*DINNER] = hi;
        ylp[(size_t)l*DINNER] = f32_to_bf16(yv - bf16_to_f32(hi));
    }
}

// ---------------------------------------------------------------------------
extern "C" void kernel_launch(void* const* d_in, const int* in_sizes, int n_in,
                              void* d_out, int out_size, void* d_ws, size_t ws_size,
                              hipStream_t stream) {
    const float* x        = (const float*)d_in[0];
    const float* x_proj   = (const float*)d_in[1];
    const float* dt_proj  = (const float*)d_in[2];
    const float* A_log    = (const float*)d_in[3];
    const float* B_proj   = (const float*)d_in[4];
    const float* C_proj   = (const float*)d_in[5];
    const float* Dvec     = (const float*)d_in[6];
    const float* out_proj = (const float*)d_in[7];
    const float* dt_bias  = (const float*)d_in[8];
    float* out = (float*)d_out;

    float* ws = (float*)d_ws;
    float* U    = ws;                                    // 8.4M floats
    float* G    = U    + (size_t)M_ROWS*DINNER;
    float* DT   = G    + (size_t)M_ROWS*DINNER;
    float* BM   = DT   + (size_t)M_ROWS*DSTATE;
    float* CM   = BM   + (size_t)M_ROWS*DSTATE;
    float* HEND = CM   + (size_t)M_ROWS*DSTATE;          // [b][chunk][d][s]
    float* PPRO = HEND + (size_t)BATCH*NCHUNK*DINNER*DSTATE;
    float* H0   = PPRO + (size_t)BATCH*NCHUNK*DINNER*DSTATE;
    u16*   Y2hi = (u16*)(H0 + (size_t)BATCH*NCHUNK*DINNER*DSTATE);
    u16*   Y2lo = Y2hi + (size_t)M_ROWS*DINNER;
    u16*   W1hi = Y2lo + (size_t)M_ROWS*DINNER;
    u16*   W1lo = W1hi + (size_t)NDIM*1024;
    u16*   W4hi = W1lo + (size_t)NDIM*1024;
    u16*   W4lo = W4hi + (size_t)DINNER*NDIM;
    // Xhi/Xlo alias Y2hi/Y2lo: X is consumed by K1 (dispatch 4) before
    // scan_phase_c (dispatch 8) writes Y2. Stream order guarantees safety.
    u16*   Xhi  = Y2hi;
    u16*   Xlo  = Y2lo;

    prep_x<<<dim3(M_ROWS*NDIM/4/256), 256, 0, stream>>>(x, Xhi, Xlo);
    prep_w<1024,10><<<dim3(NDIM*1024/256), 256, 0, stream>>>(x_proj, W1hi, W1lo);
    prep_w<256,8><<<dim3(DINNER*NDIM/256), 256, 0, stream>>>(out_proj, W4hi, W4lo);

    mfma_gemm<1024, 256, true><<<dim3(8, M_ROWS/128), 256, 0, stream>>>(
        Xhi, Xlo, W1hi, W1lo, U, G);
    proj_gemm<<<dim3(M_ROWS/64), 256, 0, stream>>>(U, dt_proj, B_proj, C_proj,
                                                   dt_bias, DT, BM, CM);
    scan_phase_a<<<dim3(NCHUNK, DINNER/256, BATCH), 256, 0, stream>>>(
        DT, BM, U, A_log, HEND, PPRO);
    scan_phase_b<<<dim3(128), 256, 0, stream>>>(HEND, PPRO, H0);
    scan_phase_c<<<dim3(NCHUNK, DINNER/256, BATCH), 256, 0, stream>>>(
        DT, BM, CM, U, G, A_log, Dvec, H0, Y2hi, Y2lo);
    mfma_gemm<256, 512, false><<<dim3(2, M_ROWS/128), 256, 0, stream>>>(
        Y2hi, Y2lo, W4hi, W4lo, out, nullptr);
}

// Round 6
// 297.450 us; speedup vs baseline: 10.2528x; 1.0863x over previous
//
#include <hip/hip_runtime.h>
#include <math.h>

#define BATCH   4
#define SEQLEN  4096
#define NDIM    256
#define DINNER  512
#define DSTATE  16
#define M_ROWS  (BATCH*SEQLEN)   // 16384
#define CHUNK   64
#define NCHUNK  (SEQLEN/CHUNK)   // 64

typedef unsigned short u16;
typedef short short8 __attribute__((ext_vector_type(8)));
typedef float floatx4 __attribute__((ext_vector_type(4)));

__device__ __forceinline__ u16 f32_to_bf16(float f) {
    union { float f; unsigned u; } v; v.f = f;
    unsigned u = v.u;
    unsigned r = (u + 0x7FFFu + ((u >> 16) & 1u)) >> 16;
    return (u16)r;
}
__device__ __forceinline__ float bf16_to_f32(u16 h) {
    union { unsigned u; float f; } v; v.u = ((unsigned)h) << 16;
    return v.f;
}

// ---------------------------------------------------------------------------
// prep_x: x (M_ROWS x 256 fp32, row-major) -> Xhi/Xlo bf16 row-major.
// ---------------------------------------------------------------------------
__global__ __launch_bounds__(256)
void prep_x(const float* __restrict__ X, u16* __restrict__ Xhi,
            u16* __restrict__ Xlo) {
    const size_t t = (size_t)blockIdx.x * 256 + threadIdx.x;
    const float4 v = ((const float4*)X)[t];
    u16 h[4], l[4];
    const float* vf = (const float*)&v;
    #pragma unroll
    for (int i = 0; i < 4; i++) {
        h[i] = f32_to_bf16(vf[i]);
        l[i] = f32_to_bf16(vf[i] - bf16_to_f32(h[i]));
    }
    uint2 hp, lp;
    hp.x = (unsigned)h[0] | ((unsigned)h[1] << 16);
    hp.y = (unsigned)h[2] | ((unsigned)h[3] << 16);
    lp.x = (unsigned)l[0] | ((unsigned)l[1] << 16);
    lp.y = (unsigned)l[2] | ((unsigned)l[3] << 16);
    ((uint2*)Xhi)[t] = hp;
    ((uint2*)Xlo)[t] = lp;
}

// ---------------------------------------------------------------------------
// prep_w: W (K x N fp32 row-major) -> packed hi/lo bf16 in B-fragment order:
// out[((kb*4+q)*N + n)*8 + j] = W[(kb*32+q*8+j)*N + n].
// ---------------------------------------------------------------------------
template<int N, int LOGN>
__global__ __launch_bounds__(256)
void prep_w(const float* __restrict__ W, u16* __restrict__ Whi,
            u16* __restrict__ Wlo) {
    const int t = blockIdx.x * 256 + threadIdx.x;
    const int j  = t & 7;
    const int n  = (t >> 3) & (N - 1);
    const int q  = (t >> (3 + LOGN)) & 3;
    const int kb = t >> (5 + LOGN);
    const int k  = kb * 32 + q * 8 + j;
    const float v = W[(size_t)k * N + n];
    const u16 hi = f32_to_bf16(v);
    Whi[t] = hi;
    Wlo[t] = f32_to_bf16(v - bf16_to_f32(hi));
}

// ---------------------------------------------------------------------------
// prep_w_proj: pack [Wdt|Wb|Wc|zeros] (512 x 64 logical) into B-frag order
// hi/lo. 32768 elements; K=512 -> kb in [0,16), N=64.
// ---------------------------------------------------------------------------
__global__ __launch_bounds__(256)
void prep_w_proj(const float* __restrict__ Wdt, const float* __restrict__ Wb,
                 const float* __restrict__ Wc, u16* __restrict__ Whi,
                 u16* __restrict__ Wlo) {
    const int t = blockIdx.x * 256 + threadIdx.x;   // < 32768
    const int j  = t & 7;
    const int n  = (t >> 3) & 63;
    const int q  = (t >> 9) & 3;
    const int kb = t >> 11;
    const int k  = kb * 32 + q * 8 + j;
    float v;
    if      (n < 16) v = Wdt[(size_t)k * 16 + n];
    else if (n < 32) v = Wb [(size_t)k * 16 + (n - 16)];
    else if (n < 48) v = Wc [(size_t)k * 16 + (n - 32)];
    else             v = 0.f;
    const u16 hi = f32_to_bf16(v);
    Whi[t] = hi;
    Wlo[t] = f32_to_bf16(v - bf16_to_f32(hi));
}

// ---------------------------------------------------------------------------
// Split-bf16 MFMA GEMM: A (M x KT, hi/lo bf16 row-major) @ W (KT x NT, packed)
// Block tile 128x128, 4 waves (2x2), each wave 64x64 = 4x4 mfma tiles.
// SILU=true: silu epilogue -> U fp32 + Uhi/Ulo bf16 (n<512), G fp32 (n>=512).
// ---------------------------------------------------------------------------
template<int NT, int KT, bool SILU>
__global__ __launch_bounds__(256)
void mfma_gemm(const u16* __restrict__ Ahi, const u16* __restrict__ Alo,
               const u16* __restrict__ Whi, const u16* __restrict__ Wlo,
               float* __restrict__ O1, float* __restrict__ O2,
               u16* __restrict__ Uh, u16* __restrict__ Ul) {
    __shared__ __attribute__((aligned(16))) u16 sAhi[128 * 40];
    __shared__ __attribute__((aligned(16))) u16 sAlo[128 * 40];
    const int tid = threadIdx.x;
    const int lane = tid & 63;
    const int w  = tid >> 6;
    const int wm = w >> 1, wn = w & 1;
    const int n0 = blockIdx.x * 128;
    const int m0 = blockIdx.y * 128;
    const int l15 = lane & 15, q = lane >> 4;

    floatx4 acc[4][4];
    const floatx4 zero = {0.f, 0.f, 0.f, 0.f};
    #pragma unroll
    for (int i = 0; i < 4; i++)
        #pragma unroll
        for (int j = 0; j < 4; j++) acc[i][j] = zero;

    for (int kb = 0; kb < KT / 32; kb++) {
        #pragma unroll
        for (int i = 0; i < 2; i++) {
            const int idx = tid + 256 * i;
            const int row = idx >> 2, c = idx & 3;
            const size_t off = (size_t)(m0 + row) * KT + kb * 32 + c * 8;
            *(float4*)(sAhi + row * 40 + c * 8) = *(const float4*)(Ahi + off);
            *(float4*)(sAlo + row * 40 + c * 8) = *(const float4*)(Alo + off);
        }
        __syncthreads();

        short8 bh[4], bl[4], ah[4], al[4];
        #pragma unroll
        for (int nt = 0; nt < 4; nt++) {
            const size_t off =
                ((size_t)((kb * 4 + q) * NT) + n0 + wn * 64 + nt * 16 + l15) * 8;
            bh[nt] = *(const short8*)(Whi + off);
            bl[nt] = *(const short8*)(Wlo + off);
        }
        #pragma unroll
        for (int mt = 0; mt < 4; mt++) {
            const int m = wm * 64 + mt * 16 + l15;
            ah[mt] = *(const short8*)(sAhi + m * 40 + q * 8);
            al[mt] = *(const short8*)(sAlo + m * 40 + q * 8);
        }
        #pragma unroll
        for (int mt = 0; mt < 4; mt++)
            #pragma unroll
            for (int nt = 0; nt < 4; nt++) {
                acc[mt][nt] = __builtin_amdgcn_mfma_f32_16x16x32_bf16(
                    ah[mt], bh[nt], acc[mt][nt], 0, 0, 0);
                acc[mt][nt] = __builtin_amdgcn_mfma_f32_16x16x32_bf16(
                    ah[mt], bl[nt], acc[mt][nt], 0, 0, 0);
                acc[mt][nt] = __builtin_amdgcn_mfma_f32_16x16x32_bf16(
                    al[mt], bh[nt], acc[mt][nt], 0, 0, 0);
            }
        __syncthreads();
    }
    // epilogue: D col=lane&15, row=quad*4+reg  [verified m89/m91]
    #pragma unroll
    for (int mt = 0; mt < 4; mt++) {
        #pragma unroll
        for (int nt = 0; nt < 4; nt++) {
            const int col = n0 + wn * 64 + nt * 16 + l15;
            #pragma unroll
            for (int r = 0; r < 4; r++) {
                const int row = m0 + wm * 64 + mt * 16 + q * 4 + r;
                float v = acc[mt][nt][r];
                if (SILU) {
                    v = v / (1.f + expf(-v));
                    if (col < DINNER) {
                        const size_t o = (size_t)row * DINNER + col;
                        O1[o] = v;
                        const u16 hi = f32_to_bf16(v);
                        Uh[o] = hi;
                        Ul[o] = f32_to_bf16(v - bf16_to_f32(hi));
                    } else {
                        O2[(size_t)row * DINNER + col - DINNER] = v;
                    }
                } else {
                    O1[(size_t)row * NT + col] = v;
                }
            }
        }
    }
}

// ---------------------------------------------------------------------------
// proj_mfma: U (16384x512 split bf16) @ Wp (512x64 packed; 48 real cols) ->
// DT (softplus+bias) / BM / CM. 256 blocks x 64 rows, 4 waves (2x2 of 32x32).
// ---------------------------------------------------------------------------
__global__ __launch_bounds__(256)
void proj_mfma(const u16* __restrict__ Uh, const u16* __restrict__ Ul,
               const u16* __restrict__ Whi, const u16* __restrict__ Wlo,
               const float* __restrict__ bias,
               float* __restrict__ DT, float* __restrict__ BM,
               float* __restrict__ CM) {
    __shared__ __attribute__((aligned(16))) u16 sAhi[64 * 40];
    __shared__ __attribute__((aligned(16))) u16 sAlo[64 * 40];
    const int tid = threadIdx.x;
    const int lane = tid & 63;
    const int w  = tid >> 6;
    const int wm = w >> 1, wn = w & 1;
    const int m0 = blockIdx.x * 64;
    const int l15 = lane & 15, q = lane >> 4;

    floatx4 acc[2][2];
    const floatx4 zero = {0.f, 0.f, 0.f, 0.f};
    #pragma unroll
    for (int i = 0; i < 2; i++)
        #pragma unroll
        for (int j = 0; j < 2; j++) acc[i][j] = zero;

    for (int kb = 0; kb < DINNER / 32; kb++) {
        {   // stage 64 rows x 32 k: 256 chunks of 8 -> 1 per thread
            const int row = tid >> 2, c = tid & 3;
            const size_t off = (size_t)(m0 + row) * DINNER + kb * 32 + c * 8;
            *(float4*)(sAhi + row * 40 + c * 8) = *(const float4*)(Uh + off);
            *(float4*)(sAlo + row * 40 + c * 8) = *(const float4*)(Ul + off);
        }
        __syncthreads();
        short8 bh[2], bl[2], ah[2], al[2];
        #pragma unroll
        for (int nt = 0; nt < 2; nt++) {
            const size_t off =
                ((size_t)((kb * 4 + q) * 64) + wn * 32 + nt * 16 + l15) * 8;
            bh[nt] = *(const short8*)(Whi + off);
            bl[nt] = *(const short8*)(Wlo + off);
        }
        #pragma unroll
        for (int mt = 0; mt < 2; mt++) {
            const int m = wm * 32 + mt * 16 + l15;
            ah[mt] = *(const short8*)(sAhi + m * 40 + q * 8);
            al[mt] = *(const short8*)(sAlo + m * 40 + q * 8);
        }
        #pragma unroll
        for (int mt = 0; mt < 2; mt++)
            #pragma unroll
            for (int nt = 0; nt < 2; nt++) {
                acc[mt][nt] = __builtin_amdgcn_mfma_f32_16x16x32_bf16(
                    ah[mt], bh[nt], acc[mt][nt], 0, 0, 0);
                acc[mt][nt] = __builtin_amdgcn_mfma_f32_16x16x32_bf16(
                    ah[mt], bl[nt], acc[mt][nt], 0, 0, 0);
                acc[mt][nt] = __builtin_amdgcn_mfma_f32_16x16x32_bf16(
                    al[mt], bh[nt], acc[mt][nt], 0, 0, 0);
            }
        __syncthreads();
    }
    #pragma unroll
    for (int mt = 0; mt < 2; mt++) {
        #pragma unroll
        for (int nt = 0; nt < 2; nt++) {
            const int col = wn * 32 + nt * 16 + l15;
            #pragma unroll
            for (int r = 0; r < 4; r++) {
                const int row = m0 + wm * 32 + mt * 16 + q * 4 + r;
                float v = acc[mt][nt][r];
                if (col < 16) {
                    float dv = v + bias[col];
                    dv = (dv > 20.f) ? dv : log1pf(expf(dv));
                    DT[(size_t)row * 16 + col] = dv;
                } else if (col < 32) {
                    BM[(size_t)row * 16 + (col - 16)] = v;
                } else if (col < 48) {
                    CM[(size_t)row * 16 + (col - 32)] = v;
                }
            }
        }
    }
}

// ---------------------------------------------------------------------------
// K3a: chunked scan phase A. One thread per d; 16 states in registers.
// ---------------------------------------------------------------------------
__global__ __launch_bounds__(256)
void scan_phase_a(const float* __restrict__ DT, const float* __restrict__ BM,
                  const float* __restrict__ Uv, const float* __restrict__ Alog,
                  float* __restrict__ HEND, float* __restrict__ PPROD) {
    __shared__ float s_dt[CHUNK][DSTATE];
    __shared__ float s_db[CHUNK][DSTATE];
    const int tid = threadIdx.x;
    const int chunk = blockIdx.x;
    const int dg = blockIdx.y;
    const int b  = blockIdx.z;
    const int d  = dg*256 + tid;
    const int l0 = chunk * CHUNK;
    {
        const float4 dtv = ((const float4*)(DT + (size_t)(b*SEQLEN + l0)*16))[tid];
        const float4 bmv = ((const float4*)(BM + (size_t)(b*SEQLEN + l0)*16))[tid];
        ((float4*)&s_dt[0][0])[tid] = dtv;
        float4 dbv;
        dbv.x = dtv.x*bmv.x; dbv.y = dtv.y*bmv.y;
        dbv.z = dtv.z*bmv.z; dbv.w = dtv.w*bmv.w;
        ((float4*)&s_db[0][0])[tid] = dbv;
    }
    __syncthreads();
    float A[DSTATE];
    #pragma unroll
    for (int qq = 0; qq < 4; qq++) {
        const float4 av = ((const float4*)(Alog + (size_t)d*16))[qq];
        A[4*qq+0] = -__expf(av.x); A[4*qq+1] = -__expf(av.y);
        A[4*qq+2] = -__expf(av.z); A[4*qq+3] = -__expf(av.w);
    }
    float h[DSTATE] = {};
    float P[DSTATE];
    #pragma unroll
    for (int s = 0; s < DSTATE; s++) P[s] = 1.f;
    const float* up = Uv + ((size_t)(b*SEQLEN + l0))*DINNER + d;
    for (int l = 0; l < CHUNK; l++) {
        const float u = up[(size_t)l*DINNER];
        #pragma unroll
        for (int s = 0; s < DSTATE; s++) {
            const float dA = __expf(s_dt[l][s] * A[s]);
            h[s] = dA*h[s] + s_db[l][s]*u;
            P[s] *= dA;
        }
    }
    float* he = HEND  + ((size_t)(b*NCHUNK + chunk)*DINNER + d)*16;
    float* pp = PPROD + ((size_t)(b*NCHUNK + chunk)*DINNER + d)*16;
    #pragma unroll
    for (int qq = 0; qq < 4; qq++) {
        float4 hv, pv;
        hv.x = h[4*qq+0]; hv.y = h[4*qq+1]; hv.z = h[4*qq+2]; hv.w = h[4*qq+3];
        pv.x = P[4*qq+0]; pv.y = P[4*qq+1]; pv.z = P[4*qq+2]; pv.w = P[4*qq+3];
        ((float4*)he)[qq] = hv;
        ((float4*)pp)[qq] = pv;
    }
}

// ---------------------------------------------------------------------------
// K3b: sequential chain over chunks. Thread per (b,d,s) = 32768.
// ---------------------------------------------------------------------------
__global__ __launch_bounds__(256)
void scan_phase_b(const float* __restrict__ HEND, const float* __restrict__ PPROD,
                  float* __restrict__ H0) {
    const int tid = threadIdx.x;
    const int s  = tid & 15;
    const int dl = tid >> 4;
    const int blk = blockIdx.x;
    const int b  = blk >> 5;
    const int dg = blk & 31;
    const int d  = dg*16 + dl;
    float h = 0.f;
    for (int c0 = 0; c0 < NCHUNK; c0 += 8) {
        float Pv[8], Hv[8];
        #pragma unroll
        for (int j = 0; j < 8; j++) {
            const size_t idx = ((size_t)(b*NCHUNK + c0 + j)*DINNER + d)*16 + s;
            Pv[j] = PPROD[idx];
            Hv[j] = HEND [idx];
        }
        #pragma unroll
        for (int j = 0; j < 8; j++) {
            H0[((size_t)(b*NCHUNK + c0 + j)*DINNER + d)*16 + s] = h;
            h = Pv[j]*h + Hv[j];
        }
    }
}

// ---------------------------------------------------------------------------
// K3c: rerun chunks from true initial state; emit Y2 as split bf16 hi/lo.
// ---------------------------------------------------------------------------
__global__ __launch_bounds__(256)
void scan_phase_c(const float* __restrict__ DT, const float* __restrict__ BM,
                  const float* __restrict__ CM, const float* __restrict__ Uv,
                  const float* __restrict__ G, const float* __restrict__ Alog,
                  const float* __restrict__ Dvec, const float* __restrict__ H0,
                  u16* __restrict__ Y2hi, u16* __restrict__ Y2lo) {
    __shared__ float s_dt[CHUNK][DSTATE];
    __shared__ float s_db[CHUNK][DSTATE];
    __shared__ float s_c [CHUNK][DSTATE];
    const int tid = threadIdx.x;
    const int chunk = blockIdx.x;
    const int dg = blockIdx.y;
    const int b  = blockIdx.z;
    const int d  = dg*256 + tid;
    const int l0 = chunk * CHUNK;
    {
        const float4 dtv = ((const float4*)(DT + (size_t)(b*SEQLEN + l0)*16))[tid];
        const float4 bmv = ((const float4*)(BM + (size_t)(b*SEQLEN + l0)*16))[tid];
        const float4 cmv = ((const float4*)(CM + (size_t)(b*SEQLEN + l0)*16))[tid];
        ((float4*)&s_dt[0][0])[tid] = dtv;
        float4 dbv;
        dbv.x = dtv.x*bmv.x; dbv.y = dtv.y*bmv.y;
        dbv.z = dtv.z*bmv.z; dbv.w = dtv.w*bmv.w;
        ((float4*)&s_db[0][0])[tid] = dbv;
        ((float4*)&s_c [0][0])[tid] = cmv;
    }
    __syncthreads();
    float A[DSTATE];
    #pragma unroll
    for (int qq = 0; qq < 4; qq++) {
        const float4 av = ((const float4*)(Alog + (size_t)d*16))[qq];
        A[4*qq+0] = -__expf(av.x); A[4*qq+1] = -__expf(av.y);
        A[4*qq+2] = -__expf(av.z); A[4*qq+3] = -__expf(av.w);
    }
    float h[DSTATE];
    {
        const float* h0 = H0 + ((size_t)(b*NCHUNK + chunk)*DINNER + d)*16;
        #pragma unroll
        for (int qq = 0; qq < 4; qq++) {
            const float4 hv = ((const float4*)h0)[qq];
            h[4*qq+0] = hv.x; h[4*qq+1] = hv.y; h[4*qq+2] = hv.z; h[4*qq+3] = hv.w;
        }
    }
    const float Dd = Dvec[d];
    const float* up = Uv + ((size_t)(b*SEQLEN + l0))*DINNER + d;
    const float* gp = G  + ((size_t)(b*SEQLEN + l0))*DINNER + d;
    u16* yhp = Y2hi + ((size_t)(b*SEQLEN + l0))*DINNER + d;
    u16* ylp = Y2lo + ((size_t)(b*SEQLEN + l0))*DINNER + d;
    for (int l = 0; l < CHUNK; l++) {
        const float u = up[(size_t)l*DINNER];
        const float g = gp[(size_t)l*DINNER];
        float y = 0.f;
        #pragma unroll
        for (int s = 0; s < DSTATE; s++) {
            const float dA = __expf(s_dt[l][s] * A[s]);
            h[s] = dA*h[s] + s_db[l][s]*u;
            y += h[s]*s_c[l][s];
        }
        const float yv = (y + u*Dd) * g;
        const u16 hi = f32_to_bf16(yv);
        yhp[(size_t)l*DINNER] = hi;
        ylp[(size_t)l*DINNER] = f32_to_bf16(yv - bf16_to_f32(hi));
    }
}

// ---------------------------------------------------------------------------
extern "C" void kernel_launch(void* const* d_in, const int* in_sizes, int n_in,
                              void* d_out, int out_size, void* d_ws, size_t ws_size,
                              hipStream_t stream) {
    const float* x        = (const float*)d_in[0];
    const float* x_proj   = (const float*)d_in[1];
    const float* dt_proj  = (const float*)d_in[2];
    const float* A_log    = (const float*)d_in[3];
    const float* B_proj   = (const float*)d_in[4];
    const float* C_proj   = (const float*)d_in[5];
    const float* Dvec     = (const float*)d_in[6];
    const float* out_proj = (const float*)d_in[7];
    const float* dt_bias  = (const float*)d_in[8];
    float* out = (float*)d_out;

    float* ws = (float*)d_ws;
    float* U    = ws;
    float* G    = U    + (size_t)M_ROWS*DINNER;
    float* DT   = G    + (size_t)M_ROWS*DINNER;
    float* BM   = DT   + (size_t)M_ROWS*DSTATE;
    float* CM   = BM   + (size_t)M_ROWS*DSTATE;
    float* HEND = CM   + (size_t)M_ROWS*DSTATE;          // [b][chunk][d][s]
    float* PPRO = HEND + (size_t)BATCH*NCHUNK*DINNER*DSTATE;
    float* H0   = PPRO + (size_t)BATCH*NCHUNK*DINNER*DSTATE;
    u16*   Y2hi = (u16*)(H0 + (size_t)BATCH*NCHUNK*DINNER*DSTATE);
    u16*   Y2lo = Y2hi + (size_t)M_ROWS*DINNER;
    u16*   W1hi = Y2lo + (size_t)M_ROWS*DINNER;
    u16*   W1lo = W1hi + (size_t)NDIM*1024;
    u16*   W4hi = W1lo + (size_t)NDIM*1024;
    u16*   W4lo = W4hi + (size_t)DINNER*NDIM;
    u16*   Wphi = W4lo + (size_t)DINNER*NDIM;            // 32768 each
    u16*   Wplo = Wphi + (size_t)32768;
    u16*   Uhi  = Wplo + (size_t)32768;                  // 16384*512 each
    u16*   Ulo  = Uhi  + (size_t)M_ROWS*DINNER;
    // Xhi/Xlo alias Y2hi/Y2lo: X consumed by K1 before scan_c writes Y2.
    u16*   Xhi  = Y2hi;
    u16*   Xlo  = Y2lo;

    prep_x<<<dim3(M_ROWS*NDIM/4/256), 256, 0, stream>>>(x, Xhi, Xlo);
    prep_w<1024,10><<<dim3(NDIM*1024/256), 256, 0, stream>>>(x_proj, W1hi, W1lo);
    prep_w<256,8><<<dim3(DINNER*NDIM/256), 256, 0, stream>>>(out_proj, W4hi, W4lo);
    prep_w_proj<<<dim3(128), 256, 0, stream>>>(dt_proj, B_proj, C_proj, Wphi, Wplo);

    mfma_gemm<1024, 256, true><<<dim3(8, M_ROWS/128), 256, 0, stream>>>(
        Xhi, Xlo, W1hi, W1lo, U, G, Uhi, Ulo);
    proj_mfma<<<dim3(M_ROWS/64), 256, 0, stream>>>(Uhi, Ulo, Wphi, Wplo,
                                                   dt_bias, DT, BM, CM);
    scan_phase_a<<<dim3(NCHUNK, DINNER/256, BATCH), 256, 0, stream>>>(
        DT, BM, U, A_log, HEND, PPRO);
    scan_phase_b<<<dim3(128), 256, 0, stream>>>(HEND, PPRO, H0);
    scan_phase_c<<<dim3(NCHUNK, DINNER/256, BATCH), 256, 0, stream>>>(
        DT, BM, CM, U, G, A_log, Dvec, H0, Y2hi, Y2lo);
    mfma_gemm<256, 512, false><<<dim3(2, M_ROWS/128), 256, 0, stream>>>(
        Y2hi, Y2lo, W4hi, W4lo, out, nullptr, nullptr, nullptr);
}

// Round 7
// 287.298 us; speedup vs baseline: 10.6151x; 1.0353x over previous
//
#include <hip/hip_runtime.h>
#include <math.h>

#define BATCH   4
#define SEQLEN  4096
#define NDIM    256
#define DINNER  512
#define DSTATE  16
#define M_ROWS  (BATCH*SEQLEN)   // 16384
#define CHUNK   64
#define NCHUNK  (SEQLEN/CHUNK)   // 64

typedef unsigned short u16;
typedef short short8 __attribute__((ext_vector_type(8)));
typedef float floatx4 __attribute__((ext_vector_type(4)));

__device__ __forceinline__ u16 f32_to_bf16(float f) {
    union { float f; unsigned u; } v; v.f = f;
    unsigned u = v.u;
    unsigned r = (u + 0x7FFFu + ((u >> 16) & 1u)) >> 16;
    return (u16)r;
}
__device__ __forceinline__ float bf16_to_f32(u16 h) {
    union { unsigned u; float f; } v; v.u = ((unsigned)h) << 16;
    return v.f;
}

// ---------------------------------------------------------------------------
// prep_x: x (M_ROWS x 256 fp32, row-major) -> Xhi/Xlo bf16 row-major.
// ---------------------------------------------------------------------------
__global__ __launch_bounds__(256)
void prep_x(const float* __restrict__ X, u16* __restrict__ Xhi,
            u16* __restrict__ Xlo) {
    const size_t t = (size_t)blockIdx.x * 256 + threadIdx.x;
    const float4 v = ((const float4*)X)[t];
    u16 h[4], l[4];
    const float* vf = (const float*)&v;
    #pragma unroll
    for (int i = 0; i < 4; i++) {
        h[i] = f32_to_bf16(vf[i]);
        l[i] = f32_to_bf16(vf[i] - bf16_to_f32(h[i]));
    }
    uint2 hp, lp;
    hp.x = (unsigned)h[0] | ((unsigned)h[1] << 16);
    hp.y = (unsigned)h[2] | ((unsigned)h[3] << 16);
    lp.x = (unsigned)l[0] | ((unsigned)l[1] << 16);
    lp.y = (unsigned)l[2] | ((unsigned)l[3] << 16);
    ((uint2*)Xhi)[t] = hp;
    ((uint2*)Xlo)[t] = lp;
}

// ---------------------------------------------------------------------------
// prep_w: W (K x N fp32) -> packed hi/lo bf16 in B-fragment order:
// out[((kb*4+q)*N + n)*8 + j] = W[(kb*32+q*8+j)*N + n].
// ---------------------------------------------------------------------------
template<int N, int LOGN>
__global__ __launch_bounds__(256)
void prep_w(const float* __restrict__ W, u16* __restrict__ Whi,
            u16* __restrict__ Wlo) {
    const int t = blockIdx.x * 256 + threadIdx.x;
    const int j  = t & 7;
    const int n  = (t >> 3) & (N - 1);
    const int q  = (t >> (3 + LOGN)) & 3;
    const int kb = t >> (5 + LOGN);
    const int k  = kb * 32 + q * 8 + j;
    const float v = W[(size_t)k * N + n];
    const u16 hi = f32_to_bf16(v);
    Whi[t] = hi;
    Wlo[t] = f32_to_bf16(v - bf16_to_f32(hi));
}

// ---------------------------------------------------------------------------
// prep_w_proj: pack [Wdt|Wb|Wc|zeros] (512 x 64 logical) into B-frag order.
// ---------------------------------------------------------------------------
__global__ __launch_bounds__(256)
void prep_w_proj(const float* __restrict__ Wdt, const float* __restrict__ Wb,
                 const float* __restrict__ Wc, u16* __restrict__ Whi,
                 u16* __restrict__ Wlo) {
    const int t = blockIdx.x * 256 + threadIdx.x;   // < 32768
    const int n  = (t >> 3) & 63;
    const int q  = (t >> 9) & 3;
    const int kb = t >> 11;
    const int k  = kb * 32 + q * 8 + (t & 7);
    float v;
    if      (n < 16) v = Wdt[(size_t)k * 16 + n];
    else if (n < 32) v = Wb [(size_t)k * 16 + (n - 16)];
    else if (n < 48) v = Wc [(size_t)k * 16 + (n - 32)];
    else             v = 0.f;
    const u16 hi = f32_to_bf16(v);
    Whi[t] = hi;
    Wlo[t] = f32_to_bf16(v - bf16_to_f32(hi));
}

// ---------------------------------------------------------------------------
// Split-bf16 MFMA GEMM. A staged in LDS in FRAGMENT ORDER:
// 16B-unit index (m, c) = ((m>>4)*4 + c)*16 + (m&15)  -> both staging writes
// and frag reads touch 64 consecutive units per wave: zero bank conflicts.
// SILU=true: silu -> split bf16 U (cols<512) / G (cols>=512). Else fp32 out.
// ---------------------------------------------------------------------------
template<int NT, int KT, bool SILU>
__global__ __launch_bounds__(256)
void mfma_gemm(const u16* __restrict__ Ahi, const u16* __restrict__ Alo,
               const u16* __restrict__ Whi, const u16* __restrict__ Wlo,
               float* __restrict__ Ofp,
               u16* __restrict__ O1h, u16* __restrict__ O1l,
               u16* __restrict__ O2h, u16* __restrict__ O2l) {
    __shared__ __attribute__((aligned(16))) u16 sAhi[128 * 32]; // 512 units
    __shared__ __attribute__((aligned(16))) u16 sAlo[128 * 32];
    const int tid = threadIdx.x;
    const int lane = tid & 63;
    const int w  = tid >> 6;
    const int wm = w >> 1, wn = w & 1;
    const int n0 = blockIdx.x * 128;
    const int m0 = blockIdx.y * 128;
    const int l15 = lane & 15, q = lane >> 4;

    floatx4 acc[4][4];
    const floatx4 zero = {0.f, 0.f, 0.f, 0.f};
    #pragma unroll
    for (int i = 0; i < 4; i++)
        #pragma unroll
        for (int j = 0; j < 4; j++) acc[i][j] = zero;

    for (int kb = 0; kb < KT / 32; kb++) {
        #pragma unroll
        for (int i = 0; i < 2; i++) {
            const int idx = tid + 256 * i;
            const int row = idx >> 2, c = idx & 3;
            const size_t off = (size_t)(m0 + row) * KT + kb * 32 + c * 8;
            const int u0 = (((row >> 4) * 4 + c) * 16 + (row & 15)) * 8;
            *(float4*)(sAhi + u0) = *(const float4*)(Ahi + off);
            *(float4*)(sAlo + u0) = *(const float4*)(Alo + off);
        }
        __syncthreads();

        short8 bh[4], bl[4], ah[4], al[4];
        #pragma unroll
        for (int nt = 0; nt < 4; nt++) {
            const size_t off =
                ((size_t)((kb * 4 + q) * NT) + n0 + wn * 64 + nt * 16 + l15) * 8;
            bh[nt] = *(const short8*)(Whi + off);
            bl[nt] = *(const short8*)(Wlo + off);
        }
        #pragma unroll
        for (int mt = 0; mt < 4; mt++) {
            const int u0 = (((wm * 4 + mt) * 4 + q) * 16 + l15) * 8;
            ah[mt] = *(const short8*)(sAhi + u0);
            al[mt] = *(const short8*)(sAlo + u0);
        }
        #pragma unroll
        for (int mt = 0; mt < 4; mt++)
            #pragma unroll
            for (int nt = 0; nt < 4; nt++) {
                acc[mt][nt] = __builtin_amdgcn_mfma_f32_16x16x32_bf16(
                    ah[mt], bh[nt], acc[mt][nt], 0, 0, 0);
                acc[mt][nt] = __builtin_amdgcn_mfma_f32_16x16x32_bf16(
                    ah[mt], bl[nt], acc[mt][nt], 0, 0, 0);
                acc[mt][nt] = __builtin_amdgcn_mfma_f32_16x16x32_bf16(
                    al[mt], bh[nt], acc[mt][nt], 0, 0, 0);
            }
        __syncthreads();
    }
    // epilogue: D col=lane&15, row=quad*4+reg  [verified m89/m91]
    #pragma unroll
    for (int mt = 0; mt < 4; mt++) {
        #pragma unroll
        for (int nt = 0; nt < 4; nt++) {
            const int col = n0 + wn * 64 + nt * 16 + l15;
            #pragma unroll
            for (int r = 0; r < 4; r++) {
                const int row = m0 + wm * 64 + mt * 16 + q * 4 + r;
                float v = acc[mt][nt][r];
                if (SILU) {
                    v = v / (1.f + __expf(-v));
                    const u16 hi = f32_to_bf16(v);
                    const u16 lo = f32_to_bf16(v - bf16_to_f32(hi));
                    if (col < DINNER) {
                        const size_t o = (size_t)row * DINNER + col;
                        O1h[o] = hi; O1l[o] = lo;
                    } else {
                        const size_t o = (size_t)row * DINNER + col - DINNER;
                        O2h[o] = hi; O2l[o] = lo;
                    }
                } else {
                    Ofp[(size_t)row * NT + col] = v;
                }
            }
        }
    }
}

// ---------------------------------------------------------------------------
// proj_mfma: U (split bf16) @ Wp (512x64 packed; 48 real cols) ->
// DT (softplus+bias) / BM / CM. Fragment-order LDS (64x32 tile, 256 units).
// ---------------------------------------------------------------------------
__global__ __launch_bounds__(256)
void proj_mfma(const u16* __restrict__ Uh, const u16* __restrict__ Ul,
               const u16* __restrict__ Whi, const u16* __restrict__ Wlo,
               const float* __restrict__ bias,
               float* __restrict__ DT, float* __restrict__ BM,
               float* __restrict__ CM) {
    __shared__ __attribute__((aligned(16))) u16 sAhi[64 * 32];
    __shared__ __attribute__((aligned(16))) u16 sAlo[64 * 32];
    const int tid = threadIdx.x;
    const int lane = tid & 63;
    const int w  = tid >> 6;
    const int wm = w >> 1, wn = w & 1;
    const int m0 = blockIdx.x * 64;
    const int l15 = lane & 15, q = lane >> 4;

    floatx4 acc[2][2];
    const floatx4 zero = {0.f, 0.f, 0.f, 0.f};
    #pragma unroll
    for (int i = 0; i < 2; i++)
        #pragma unroll
        for (int j = 0; j < 2; j++) acc[i][j] = zero;

    for (int kb = 0; kb < DINNER / 32; kb++) {
        {
            const int row = tid >> 2, c = tid & 3;
            const size_t off = (size_t)(m0 + row) * DINNER + kb * 32 + c * 8;
            const int u0 = (((row >> 4) * 4 + c) * 16 + (row & 15)) * 8;
            *(float4*)(sAhi + u0) = *(const float4*)(Uh + off);
            *(float4*)(sAlo + u0) = *(const float4*)(Ul + off);
        }
        __syncthreads();
        short8 bh[2], bl[2], ah[2], al[2];
        #pragma unroll
        for (int nt = 0; nt < 2; nt++) {
            const size_t off =
                ((size_t)((kb * 4 + q) * 64) + wn * 32 + nt * 16 + l15) * 8;
            bh[nt] = *(const short8*)(Whi + off);
            bl[nt] = *(const short8*)(Wlo + off);
        }
        #pragma unroll
        for (int mt = 0; mt < 2; mt++) {
            const int u0 = (((wm * 2 + mt) * 4 + q) * 16 + l15) * 8;
            ah[mt] = *(const short8*)(sAhi + u0);
            al[mt] = *(const short8*)(sAlo + u0);
        }
        #pragma unroll
        for (int mt = 0; mt < 2; mt++)
            #pragma unroll
            for (int nt = 0; nt < 2; nt++) {
                acc[mt][nt] = __builtin_amdgcn_mfma_f32_16x16x32_bf16(
                    ah[mt], bh[nt], acc[mt][nt], 0, 0, 0);
                acc[mt][nt] = __builtin_amdgcn_mfma_f32_16x16x32_bf16(
                    ah[mt], bl[nt], acc[mt][nt], 0, 0, 0);
                acc[mt][nt] = __builtin_amdgcn_mfma_f32_16x16x32_bf16(
                    al[mt], bh[nt], acc[mt][nt], 0, 0, 0);
            }
        __syncthreads();
    }
    #pragma unroll
    for (int mt = 0; mt < 2; mt++) {
        #pragma unroll
        for (int nt = 0; nt < 2; nt++) {
            const int col = wn * 32 + nt * 16 + l15;
            #pragma unroll
            for (int r = 0; r < 4; r++) {
                const int row = m0 + wm * 32 + mt * 16 + q * 4 + r;
                float v = acc[mt][nt][r];
                if (col < 16) {
                    float dv = v + bias[col];
                    dv = (dv > 20.f) ? dv : log1pf(__expf(dv));
                    DT[(size_t)row * 16 + col] = dv;
                } else if (col < 32) {
                    BM[(size_t)row * 16 + (col - 16)] = v;
                } else if (col < 48) {
                    CM[(size_t)row * 16 + (col - 32)] = v;
                }
            }
        }
    }
}

// ---------------------------------------------------------------------------
// K3a: chunked scan phase A. One thread per d; 16 states in registers.
// u reconstructed exactly from split bf16 (hi + lo).
// ---------------------------------------------------------------------------
__global__ __launch_bounds__(256)
void scan_phase_a(const float* __restrict__ DT, const float* __restrict__ BM,
                  const u16* __restrict__ Uh, const u16* __restrict__ Ul,
                  const float* __restrict__ Alog,
                  float* __restrict__ HEND, float* __restrict__ PPROD) {
    __shared__ float s_dt[CHUNK][DSTATE];
    __shared__ float s_db[CHUNK][DSTATE];
    const int tid = threadIdx.x;
    const int chunk = blockIdx.x;
    const int dg = blockIdx.y;
    const int b  = blockIdx.z;
    const int d  = dg*256 + tid;
    const int l0 = chunk * CHUNK;
    {
        const float4 dtv = ((const float4*)(DT + (size_t)(b*SEQLEN + l0)*16))[tid];
        const float4 bmv = ((const float4*)(BM + (size_t)(b*SEQLEN + l0)*16))[tid];
        ((float4*)&s_dt[0][0])[tid] = dtv;
        float4 dbv;
        dbv.x = dtv.x*bmv.x; dbv.y = dtv.y*bmv.y;
        dbv.z = dtv.z*bmv.z; dbv.w = dtv.w*bmv.w;
        ((float4*)&s_db[0][0])[tid] = dbv;
    }
    __syncthreads();
    float A[DSTATE];
    #pragma unroll
    for (int qq = 0; qq < 4; qq++) {
        const float4 av = ((const float4*)(Alog + (size_t)d*16))[qq];
        A[4*qq+0] = -__expf(av.x); A[4*qq+1] = -__expf(av.y);
        A[4*qq+2] = -__expf(av.z); A[4*qq+3] = -__expf(av.w);
    }
    float h[DSTATE] = {};
    float P[DSTATE];
    #pragma unroll
    for (int s = 0; s < DSTATE; s++) P[s] = 1.f;
    const u16* uhp = Uh + ((size_t)(b*SEQLEN + l0))*DINNER + d;
    const u16* ulp = Ul + ((size_t)(b*SEQLEN + l0))*DINNER + d;
    for (int l = 0; l < CHUNK; l++) {
        const float u = bf16_to_f32(uhp[(size_t)l*DINNER])
                      + bf16_to_f32(ulp[(size_t)l*DINNER]);
        #pragma unroll
        for (int s = 0; s < DSTATE; s++) {
            const float dA = __expf(s_dt[l][s] * A[s]);
            h[s] = dA*h[s] + s_db[l][s]*u;
            P[s] *= dA;
        }
    }
    float* he = HEND  + ((size_t)(b*NCHUNK + chunk)*DINNER + d)*16;
    float* pp = PPROD + ((size_t)(b*NCHUNK + chunk)*DINNER + d)*16;
    #pragma unroll
    for (int qq = 0; qq < 4; qq++) {
        float4 hv, pv;
        hv.x = h[4*qq+0]; hv.y = h[4*qq+1]; hv.z = h[4*qq+2]; hv.w = h[4*qq+3];
        pv.x = P[4*qq+0]; pv.y = P[4*qq+1]; pv.z = P[4*qq+2]; pv.w = P[4*qq+3];
        ((float4*)he)[qq] = hv;
        ((float4*)pp)[qq] = pv;
    }
}

// ---------------------------------------------------------------------------
// K3b: sequential chain over chunks. Thread per (b,d,s) = 32768.
// ---------------------------------------------------------------------------
__global__ __launch_bounds__(256)
void scan_phase_b(const float* __restrict__ HEND, const float* __restrict__ PPROD,
                  float* __restrict__ H0) {
    const int tid = threadIdx.x;
    const int s  = tid & 15;
    const int dl = tid >> 4;
    const int blk = blockIdx.x;
    const int b  = blk >> 5;
    const int dg = blk & 31;
    const int d  = dg*16 + dl;
    float h = 0.f;
    for (int c0 = 0; c0 < NCHUNK; c0 += 8) {
        float Pv[8], Hv[8];
        #pragma unroll
        for (int j = 0; j < 8; j++) {
            const size_t idx = ((size_t)(b*NCHUNK + c0 + j)*DINNER + d)*16 + s;
            Pv[j] = PPROD[idx];
            Hv[j] = HEND [idx];
        }
        #pragma unroll
        for (int j = 0; j < 8; j++) {
            H0[((size_t)(b*NCHUNK + c0 + j)*DINNER + d)*16 + s] = h;
            h = Pv[j]*h + Hv[j];
        }
    }
}

// ---------------------------------------------------------------------------
// K3c: rerun chunks from true initial state; u,g reconstructed from split
// bf16; emit Y2 as split bf16 hi/lo (feeds MFMA K4).
// ---------------------------------------------------------------------------
__global__ __launch_bounds__(256)
void scan_phase_c(const float* __restrict__ DT, const float* __restrict__ BM,
                  const float* __restrict__ CM,
                  const u16* __restrict__ Uh, const u16* __restrict__ Ul,
                  const u16* __restrict__ Gh, const u16* __restrict__ Gl,
                  const float* __restrict__ Alog,
                  const float* __restrict__ Dvec, const float* __restrict__ H0,
                  u16* __restrict__ Y2hi, u16* __restrict__ Y2lo) {
    __shared__ float s_dt[CHUNK][DSTATE];
    __shared__ float s_db[CHUNK][DSTATE];
    __shared__ float s_c [CHUNK][DSTATE];
    const int tid = threadIdx.x;
    const int chunk = blockIdx.x;
    const int dg = blockIdx.y;
    const int b  = blockIdx.z;
    const int d  = dg*256 + tid;
    const int l0 = chunk * CHUNK;
    {
        const float4 dtv = ((const float4*)(DT + (size_t)(b*SEQLEN + l0)*16))[tid];
        const float4 bmv = ((const float4*)(BM + (size_t)(b*SEQLEN + l0)*16))[tid];
        const float4 cmv = ((const float4*)(CM + (size_t)(b*SEQLEN + l0)*16))[tid];
        ((float4*)&s_dt[0][0])[tid] = dtv;
        float4 dbv;
        dbv.x = dtv.x*bmv.x; dbv.y = dtv.y*bmv.y;
        dbv.z = dtv.z*bmv.z; dbv.w = dtv.w*bmv.w;
        ((float4*)&s_db[0][0])[tid] = dbv;
        ((float4*)&s_c [0][0])[tid] = cmv;
    }
    __syncthreads();
    float A[DSTATE];
    #pragma unroll
    for (int qq = 0; qq < 4; qq++) {
        const float4 av = ((const float4*)(Alog + (size_t)d*16))[qq];
        A[4*qq+0] = -__expf(av.x); A[4*qq+1] = -__expf(av.y);
        A[4*qq+2] = -__expf(av.z); A[4*qq+3] = -__expf(av.w);
    }
    float h[DSTATE];
    {
        const float* h0 = H0 + ((size_t)(b*NCHUNK + chunk)*DINNER + d)*16;
        #pragma unroll
        for (int qq = 0; qq < 4; qq++) {
            const float4 hv = ((const float4*)h0)[qq];
            h[4*qq+0] = hv.x; h[4*qq+1] = hv.y; h[4*qq+2] = hv.z; h[4*qq+3] = hv.w;
        }
    }
    const float Dd = Dvec[d];
    const size_t base = ((size_t)(b*SEQLEN + l0))*DINNER + d;
    const u16* uhp = Uh + base;
    const u16* ulp = Ul + base;
    const u16* ghp = Gh + base;
    const u16* glp = Gl + base;
    u16* yhp = Y2hi + base;
    u16* ylp = Y2lo + base;
    for (int l = 0; l < CHUNK; l++) {
        const float u = bf16_to_f32(uhp[(size_t)l*DINNER])
                      + bf16_to_f32(ulp[(size_t)l*DINNER]);
        const float g = bf16_to_f32(ghp[(size_t)l*DINNER])
                      + bf16_to_f32(glp[(size_t)l*DINNER]);
        float y = 0.f;
        #pragma unroll
        for (int s = 0; s < DSTATE; s++) {
            const float dA = __expf(s_dt[l][s] * A[s]);
            h[s] = dA*h[s] + s_db[l][s]*u;
            y += h[s]*s_c[l][s];
        }
        const float yv = (y + u*Dd) * g;
        const u16 hi = f32_to_bf16(yv);
        yhp[(size_t)l*DINNER] = hi;
        ylp[(size_t)l*DINNER] = f32_to_bf16(yv - bf16_to_f32(hi));
    }
}

// ---------------------------------------------------------------------------
extern "C" void kernel_launch(void* const* d_in, const int* in_sizes, int n_in,
                              void* d_out, int out_size, void* d_ws, size_t ws_size,
                              hipStream_t stream) {
    const float* x        = (const float*)d_in[0];
    const float* x_proj   = (const float*)d_in[1];
    const float* dt_proj  = (const float*)d_in[2];
    const float* A_log    = (const float*)d_in[3];
    const float* B_proj   = (const float*)d_in[4];
    const float* C_proj   = (const float*)d_in[5];
    const float* Dvec     = (const float*)d_in[6];
    const float* out_proj = (const float*)d_in[7];
    const float* dt_bias  = (const float*)d_in[8];
    float* out = (float*)d_out;

    float* ws = (float*)d_ws;
    float* DT   = ws;                                    // 16384*16
    float* BM   = DT   + (size_t)M_ROWS*DSTATE;
    float* CM   = BM   + (size_t)M_ROWS*DSTATE;
    float* HEND = CM   + (size_t)M_ROWS*DSTATE;          // [b][chunk][d][s]
    float* PPRO = HEND + (size_t)BATCH*NCHUNK*DINNER*DSTATE;
    float* H0   = PPRO + (size_t)BATCH*NCHUNK*DINNER*DSTATE;
    u16*   Y2hi = (u16*)(H0 + (size_t)BATCH*NCHUNK*DINNER*DSTATE);
    u16*   Y2lo = Y2hi + (size_t)M_ROWS*DINNER;
    u16*   W1hi = Y2lo + (size_t)M_ROWS*DINNER;
    u16*   W1lo = W1hi + (size_t)NDIM*1024;
    u16*   W4hi = W1lo + (size_t)NDIM*1024;
    u16*   W4lo = W4hi + (size_t)DINNER*NDIM;
    u16*   Wphi = W4lo + (size_t)DINNER*NDIM;            // 32768 each
    u16*   Wplo = Wphi + (size_t)32768;
    u16*   Uhi  = Wplo + (size_t)32768;                  // 16384*512 each
    u16*   Ulo  = Uhi  + (size_t)M_ROWS*DINNER;
    u16*   Ghi  = Ulo  + (size_t)M_ROWS*DINNER;
    u16*   Glo  = Ghi  + (size_t)M_ROWS*DINNER;
    // Xhi/Xlo alias Y2hi/Y2lo: X consumed by K1 before scan_c writes Y2.
    u16*   Xhi  = Y2hi;
    u16*   Xlo  = Y2lo;

    prep_x<<<dim3(M_ROWS*NDIM/4/256), 256, 0, stream>>>(x, Xhi, Xlo);
    prep_w<1024,10><<<dim3(NDIM*1024/256), 256, 0, stream>>>(x_proj, W1hi, W1lo);
    prep_w<256,8><<<dim3(DINNER*NDIM/256), 256, 0, stream>>>(out_proj, W4hi, W4lo);
    prep_w_proj<<<dim3(128), 256, 0, stream>>>(dt_proj, B_proj, C_proj, Wphi, Wplo);

    mfma_gemm<1024, 256, true><<<dim3(8, M_ROWS/128), 256, 0, stream>>>(
        Xhi, Xlo, W1hi, W1lo, nullptr, Uhi, Ulo, Ghi, Glo);
    proj_mfma<<<dim3(M_ROWS/64), 256, 0, stream>>>(Uhi, Ulo, Wphi, Wplo,
                                                   dt_bias, DT, BM, CM);
    scan_phase_a<<<dim3(NCHUNK, DINNER/256, BATCH), 256, 0, stream>>>(
        DT, BM, Uhi, Ulo, A_log, HEND, PPRO);
    scan_phase_b<<<dim3(128), 256, 0, stream>>>(HEND, PPRO, H0);
    scan_phase_c<<<dim3(NCHUNK, DINNER/256, BATCH), 256, 0, stream>>>(
        DT, BM, CM, Uhi, Ulo, Ghi, Glo, A_log, Dvec, H0, Y2hi, Y2lo);
    mfma_gemm<256, 512, false><<<dim3(2, M_ROWS/128), 256, 0, stream>>>(
        Y2hi, Y2lo, W4hi, W4lo, out, nullptr, nullptr, nullptr, nullptr);
}